// Round 9
// baseline (590.639 us; speedup 1.0000x reference)
//
#include <hip/hip_runtime.h>
#include <hip/hip_cooperative_groups.h>

namespace cg = cooperative_groups;

typedef unsigned short u16;
typedef __bf16 bf16x8 __attribute__((ext_vector_type(8)));
typedef float f32x4 __attribute__((ext_vector_type(4)));

#define N_ 16384
#define SCALE 0.35355339059327379f   // 64^-0.25

__device__ __forceinline__ u16 f2bf(float f){
  union { float f; unsigned int i; } v; v.f = f;
  unsigned int b = v.i;
  return (u16)((b + 0x7FFFu + ((b >> 16) & 1u)) >> 16);
}
// packed RNE f32x2 -> bf16x2 (bit-identical to f2bf pair, 1 instr)
__device__ __forceinline__ unsigned int cvtpk(float a, float b){
  unsigned int r;
  asm("v_cvt_pk_bf16_f32 %0, %1, %2" : "=v"(r) : "v"(a), "v"(b));
  return r;
}

// ===========================================================================
// FUSED cooperative kernel: P0 conv+prep | P1 kvctx | P2 redmker | P3 qout
// 512 blocks x 256 thr, 2 blocks/CU co-resident (64 KiB LDS, VGPR<=256).
// Phase bodies are the R7/R8-measured kernels verbatim; only block->unit
// indexing changed. grid.sync() replaces kernel boundaries.
// ===========================================================================
__global__ __launch_bounds__(256, 2) void fused(
    const float* __restrict__ x,  const float* __restrict__ Wq,
    const float* __restrict__ bq, const float* __restrict__ Wk,
    const float* __restrict__ bk, const float* __restrict__ Wv,
    const float* __restrict__ bv, const float* __restrict__ Wo,
    const float* __restrict__ bo, float* __restrict__ out,
    u16* __restrict__ xt, u16* __restrict__ wkvf, u16* __restrict__ wqf,
    u16* __restrict__ mtf, float* __restrict__ bkv, float* __restrict__ bqs,
    float* __restrict__ pctx, float* __restrict__ prs)
{
  __shared__ __align__(16) char SM[65536];
  const int bid = blockIdx.x;   // 0..511
  const int tid = threadIdx.x;

  // ===================== P0: convx (unit = bid) ===========================
  {
    const int b = bid >> 7;
    const int kq = tid >> 6;                           // wave = k-quarter
    const int t0 = (bid & 127) * 128 + 2 * (tid & 63); // 2 tokens / thread
    const float* xp = x + (size_t)(b * 128 + kq * 32) * N_ + t0;
    u16* dst = xt + (size_t)(b * N_ + t0) * 128;
#pragma unroll
    for (int gi = 0; gi < 4; gi++){
      float2 v[8];
#pragma unroll
      for (int j = 0; j < 8; j++)
        v[j] = *(const float2*)(xp + (size_t)(gi * 8 + j) * N_);
      const int g = kq * 4 + gi;
      {
        uint4 o;
        o.x = cvtpk(v[0].x, v[1].x); o.y = cvtpk(v[2].x, v[3].x);
        o.z = cvtpk(v[4].x, v[5].x); o.w = cvtpk(v[6].x, v[7].x);
        *(uint4*)(dst + ((g ^ (t0 & 15)) * 8)) = o;
      }
      {
        uint4 o;
        o.x = cvtpk(v[0].y, v[1].y); o.y = cvtpk(v[2].y, v[3].y);
        o.z = cvtpk(v[4].y, v[5].y); o.w = cvtpk(v[6].y, v[7].y);
        const int t = t0 + 1;
        *(uint4*)(dst + 128 + ((g ^ (t & 15)) * 8)) = o;
      }
    }
  }
  // ---- P0b: prep (blocks 0..95) ----
  if (bid < 96){
    const int T = bid * 256 + tid;   // 0..24575
    if (T < 1024){
      int jj = T & 127, h = T >> 7;
      bkv[T] = (jj < 64) ? SCALE * bk[h * 64 + jj] : bv[h * 64 + jj - 64];
    } else if (T < 1536){
      bqs[T - 1024] = SCALE * bq[T - 1024];
    }
    const float* src; float sc; u16* dst;
    if (T < 16384){
      int l = T & 63, f = T >> 6;
      int ks = f & 3, jt = (f >> 2) & 7, h = f >> 5;
      int jj = 16 * jt + (l & 15);
      int k0 = ks * 32 + (l >> 4) * 8;
      if (jj < 64){ src = Wk + (size_t)(h * 64 + jj) * 128 + k0; sc = SCALE; }
      else        { src = Wv + (size_t)(h * 64 + jj - 64) * 128 + k0; sc = 1.f; }
      dst = wkvf + (size_t)f * 512 + l * 8;
    } else {
      int T2 = T - 16384;
      int l = T2 & 63, f = T2 >> 6;
      int ks = f & 3, dt = (f >> 2) & 3, h = f >> 4;
      int d = 16 * dt + (l & 15);
      int k0 = ks * 32 + (l >> 4) * 8;
      src = Wq + (size_t)(h * 64 + d) * 128 + k0; sc = SCALE;
      dst = wqf + (size_t)f * 512 + l * 8;
    }
    float4 a = *(const float4*)src, c = *(const float4*)(src + 4);
    ushort4 o0, o1;
    o0.x = f2bf(sc * a.x); o0.y = f2bf(sc * a.y); o0.z = f2bf(sc * a.z); o0.w = f2bf(sc * a.w);
    o1.x = f2bf(sc * c.x); o1.y = f2bf(sc * c.y); o1.z = f2bf(sc * c.z); o1.w = f2bf(sc * c.w);
    *(ushort4*)dst = o0; *(ushort4*)(dst + 4) = o1;
  }
  __threadfence();
  cg::this_grid().sync();

  // ===================== P1: kvctx (units bid, bid+512) ===================
  {
    u16* smem = (u16*)SM;
    const int w = tid >> 6, l = tid & 63, r15 = l & 15, q = l >> 4;
    const int th = w & 1, jh = w >> 1;
    for (int u = bid; u < 1024; u += 512){
      const int chunk = u & 31, h = (u >> 5) & 7, b = u >> 8;
      __syncthreads();   // all waves past previous unit's fb reads

      bf16x8 wf[4][4];
#pragma unroll
      for (int ni = 0; ni < 4; ni++)
#pragma unroll
        for (int ks = 0; ks < 4; ks++)
          wf[ni][ks] = *(const bf16x8*)(wkvf +
              (size_t)((h * 8 + 4 * jh + ni) * 4 + ks) * 512 + l * 8);
      float barr[4];
#pragma unroll
      for (int ni = 0; ni < 4; ni++)
        barr[ni] = bkv[h * 128 + jh * 64 + 16 * ni + r15];

      const size_t tok0 = (size_t)b * N_ + chunk * 512;
      const char* gbase = (const char*)(xt + tok0 * 128);  // 512 rows x 256 B
      u16* sekv = smem + 16384;

#define STAGE(sub_)                                                            \
  {                                                                            \
    const char* gs = gbase + (size_t)(sub_)*32768 + w * 8192 + l * 16;         \
    char* ls = (char*)smem + w * 8192;                                         \
    _Pragma("unroll")                                                          \
    for (int p = 0; p < 8; p++)                                                \
      __builtin_amdgcn_global_load_lds(                                        \
          (const __attribute__((address_space(1))) void*)(gs + p * 1024),      \
          (__attribute__((address_space(3))) void*)(ls + p * 1024), 16, 0, 0); \
  }

      STAGE(0);
      __syncthreads();   // sub0 x-tile ready

      f32x4 acc2[4][4] = {};
      float rs[4] = {0.f, 0.f, 0.f, 0.f};

      for (int sub = 0; sub < 4; sub++){
        f32x4 acc1[4][4] = {};
#pragma unroll
        for (int ks = 0; ks < 4; ks++){
          bf16x8 xa[4];
#pragma unroll
          for (int mi = 0; mi < 4; mi++){
            int t = th * 64 + 16 * mi + r15;
            xa[mi] = *(const bf16x8*)&smem[t * 128 + (((ks * 4 + q) ^ r15) * 8)];
          }
#pragma unroll
          for (int mi = 0; mi < 4; mi++)
#pragma unroll
            for (int ni = 0; ni < 4; ni++)
              acc1[mi][ni] = __builtin_amdgcn_mfma_f32_16x16x32_bf16(
                  xa[mi], wf[ni][ks], acc1[mi][ni], 0, 0, 0);
        }
        // B0 (lgkm-only): all waves done READING sx -> safe to overwrite
        asm volatile("s_waitcnt lgkmcnt(0)" ::: "memory");
        __builtin_amdgcn_s_barrier();
        if (sub < 3) STAGE(sub + 1);   // flies under softmax + MFMA2
#pragma unroll
        for (int ni = 0; ni < 4; ni++){
          const float bb = barr[ni];
          const int j = jh * 64 + 16 * ni + r15;
          float ps = 0.f;
#pragma unroll
          for (int mi = 0; mi < 4; mi++){
            float vals[4];
#pragma unroll
            for (int r = 0; r < 4; r++) vals[r] = acc1[mi][ni][r] + bb;
            if (jh == 0){
#pragma unroll
              for (int r = 0; r < 4; r++){ vals[r] = __expf(vals[r]); ps += vals[r]; }
            }
            uint2 pk;
            pk.x = cvtpk(vals[0], vals[1]);
            pk.y = cvtpk(vals[2], vals[3]);
            int g8 = 16 * th + 4 * mi + q;
            int g8s = g8 ^ (2 * r15);
            *(uint2*)&sekv[j * 128 + g8s * 4] = pk;
          }
          if (jh == 0){
            ps += __shfl_xor(ps, 16); ps += __shfl_xor(ps, 32);
            rs[ni] += ps;
          }
        }
        // B1 (lgkm-only): sekv visible; staging vmcnt NOT drained
        asm volatile("s_waitcnt lgkmcnt(0)" ::: "memory");
        __builtin_amdgcn_s_barrier();
        {
          bf16x8 ka[4], va[4];
          const int g8s = (8 * w + 2 * q) ^ (2 * r15);
#pragma unroll
          for (int mi2 = 0; mi2 < 4; mi2++){
            int d = 16 * mi2 + r15;
            ka[mi2] = *(const bf16x8*)&sekv[d * 128 + g8s * 4];
          }
#pragma unroll
          for (int ni2 = 0; ni2 < 4; ni2++){
            int e = 16 * ni2 + r15;
            va[ni2] = *(const bf16x8*)&sekv[(64 + e) * 128 + g8s * 4];
          }
#pragma unroll
          for (int mi2 = 0; mi2 < 4; mi2++)
#pragma unroll
            for (int ni2 = 0; ni2 < 4; ni2++)
              acc2[mi2][ni2] = __builtin_amdgcn_mfma_f32_16x16x32_bf16(
                  ka[mi2], va[ni2], acc2[mi2][ni2], 0, 0, 0);
        }
        __syncthreads();   // B2 (full): staged sx ready; sekv consumed
      }
#undef STAGE
      float* fb = (float*)smem;
#pragma unroll
      for (int mi2 = 0; mi2 < 4; mi2++)
#pragma unroll
        for (int ni2 = 0; ni2 < 4; ni2++)
#pragma unroll
          for (int r = 0; r < 4; r++){
            int d = 16 * mi2 + 4 * q + r, e = 16 * ni2 + r15;
            fb[w * 4096 + d * 64 + e] = acc2[mi2][ni2][r];
          }
      __syncthreads();
      {
        float* dst = pctx + ((size_t)((b * 8 + h) * 32 + chunk)) * 4096 + tid * 16;
#pragma unroll
        for (int i = 0; i < 4; i++){
          int o = tid * 16 + 4 * i;
          float4 a = *(const float4*)(fb + o);
          float4 c = *(const float4*)(fb + 4096 + o);
          float4 d = *(const float4*)(fb + 8192 + o);
          float4 e = *(const float4*)(fb + 12288 + o);
          float4 s;
          s.x = a.x + c.x + d.x + e.x; s.y = a.y + c.y + d.y + e.y;
          s.z = a.z + c.z + d.z + e.z; s.w = a.w + c.w + d.w + e.w;
          *(float4*)(dst + 4 * i) = s;
        }
      }
      if (jh == 0 && q == 0){
        float* rb = prs + ((size_t)((b * 8 + h) * 32 + chunk)) * 128 + th * 64;
#pragma unroll
        for (int ni = 0; ni < 4; ni++) rb[16 * ni + r15] = rs[ni];
      }
    }
  }
  __threadfence();
  cg::this_grid().sync();

  // ===================== P2: redmker (blocks 0..255) ======================
  if (bid < 256){
    const int bh = bid & 31, s = bid >> 5;
    const int h = bh & 7;
    float* ctxh8 = (float*)SM;                 // [8][68]
    float* woht  = (float*)(SM + 2176);        // [64][132]
    float* rsh   = (float*)(SM + 2176 + 33792);// [8]
    { // stage Wo^T slice for head h
      const int e4 = tid & 15, r0 = tid >> 4;
#pragma unroll
      for (int p = 0; p < 8; p++){
        int c = r0 + p * 16;
        float4 v = *(const float4*)(Wo + (size_t)c * 512 + h * 64 + 4 * e4);
        woht[(4 * e4 + 0) * 132 + c] = v.x; woht[(4 * e4 + 1) * 132 + c] = v.y;
        woht[(4 * e4 + 2) * 132 + c] = v.z; woht[(4 * e4 + 3) * 132 + c] = v.w;
      }
    }
    { // reduce 32 chunk-partials of this 512-float slice (float2/thread)
      const float* base = pctx + (size_t)bh * 131072 + s * 512 + tid * 2;
      float2 a = {0.f, 0.f};
#pragma unroll 4
      for (int c = 0; c < 32; c++){
        float2 v = *(const float2*)(base + c * 4096);
        a.x += v.x; a.y += v.y;
      }
      const int i = tid * 2;
      ctxh8[(i >> 6) * 68 + (i & 63)] = a.x;
      ctxh8[((i + 1) >> 6) * 68 + ((i + 1) & 63)] = a.y;
    }
    { // rowsum for the 8 d-rows of this slice
      const int dl = tid >> 5, c = tid & 31;
      const int dg = s * 8 + dl;
      const float* rb = prs + (size_t)bh * 4096 + c * 128;
      float v = rb[dg] + rb[64 + dg];
      v += __shfl_xor(v, 1);  v += __shfl_xor(v, 2);
      v += __shfl_xor(v, 4);  v += __shfl_xor(v, 8);
      v += __shfl_xor(v, 16);
      if (c == 0) rsh[dl] = v;
    }
    __syncthreads();
    const int dl = tid >> 5, c0 = (tid & 31) * 4;
    const int d = s * 8 + dl;
    const float inv = 1.f / rsh[dl];
    float acc[4] = {0.f, 0.f, 0.f, 0.f};
    for (int e = 0; e < 64; e++){
      float cv = ctxh8[dl * 68 + e];
#pragma unroll
      for (int j = 0; j < 4; j++) acc[j] += cv * woht[e * 132 + c0 + j];
    }
    const int ks = d >> 5, lq = ((d >> 3) & 3) << 4, el = d & 7;
#pragma unroll
    for (int j = 0; j < 4; j++){
      int c = c0 + j;
      mtf[((size_t)(bh * 8 + (c >> 4)) * 2 + ks) * 512 + ((c & 15) | lq) * 8 + el]
          = f2bf(inv * acc[j]);
    }
  }
  __threadfence();
  cg::this_grid().sync();

  // ===================== P3: qout v7 (units bid, bid+512) =================
  {
    const int w = tid >> 6, l = tid & 63, r15 = l & 15, q = l >> 4;
    const int m7 = 2 * (r15 & 7);
    u16* sp = (u16*)SM + w * 1024;   // wave-private p[16t][64d]
    for (int u = bid; u < 1024; u += 512){
      const int tt = u & 255, b = u >> 8;
      const int t0 = tt * 64;
      const int t = t0 + w * 16 + r15;

      // x B-frags for this wave's 16 tokens (h-independent, pre-swizzled xt)
      bf16x8 xb[4];
#pragma unroll
      for (int ks = 0; ks < 4; ks++)
        xb[ks] = *(const bf16x8*)(xt + (size_t)(b * N_ + t) * 128 +
                                  (((ks * 4 + q) ^ r15) * 8));

      f32x4 acc3[8] = {};
      for (int h = 0; h < 8; h++){
        float bq_[4][4];
#pragma unroll
        for (int mi = 0; mi < 4; mi++){
          float4 v = *(const float4*)(bqs + h * 64 + 16 * mi + 4 * q);
          bq_[mi][0] = v.x; bq_[mi][1] = v.y; bq_[mi][2] = v.z; bq_[mi][3] = v.w;
        }
        // MFMA1: D[d 64][t 16], K=128; A = wq frags (L2), B = xb (regs)
        f32x4 acc1[4] = {};
#pragma unroll
        for (int ks = 0; ks < 4; ks++){
          bf16x8 wqv[4];
#pragma unroll
          for (int mi = 0; mi < 4; mi++)
            wqv[mi] = *(const bf16x8*)(wqf +
                (size_t)((h * 4 + mi) * 4 + ks) * 512 + l * 8);
#pragma unroll
          for (int mi = 0; mi < 4; mi++)
            acc1[mi] = __builtin_amdgcn_mfma_f32_16x16x32_bf16(
                wqv[mi], xb[ks], acc1[mi], 0, 0, 0);
        }
        // prefetch ks2=0 mf frags (independent of softmax)
        bf16x8 mfA[4], mfB[4];
#pragma unroll
        for (int mm = 0; mm < 4; mm++)
          mfA[mm] = *(const bf16x8*)(mtf +
              ((size_t)((b * 8 + h) * 8 + mm) * 2 + 0) * 512 + l * 8);
#pragma unroll
        for (int mm = 0; mm < 4; mm++)
          mfB[mm] = *(const bf16x8*)(mtf +
              ((size_t)((b * 8 + h) * 8 + 4 + mm) * 2 + 0) * 512 + l * 8);
        // exp + in-wave colsum + normalized p store (wave-private)
        {
          float ps = 0.f;
#pragma unroll
          for (int mi = 0; mi < 4; mi++)
#pragma unroll
            for (int r = 0; r < 4; r++){
              float e = __expf(acc1[mi][r] + bq_[mi][r]);
              acc1[mi][r] = e; ps += e;
            }
          ps += __shfl_xor(ps, 16); ps += __shfl_xor(ps, 32);
          const float ci = 1.f / ps;
#pragma unroll
          for (int mi = 0; mi < 4; mi++){
            uint2 pk;
            pk.x = cvtpk(acc1[mi][0] * ci, acc1[mi][1] * ci);
            pk.y = cvtpk(acc1[mi][2] * ci, acc1[mi][3] * ci);
            int g8s = (4 * mi + q) ^ m7;
            *(uint2*)&sp[r15 * 64 + g8s * 4] = pk;
          }
        }
        // MFMA2 with X/Y rotation
        bf16x8 pb0 = *(const bf16x8*)&sp[r15 * 64 + (((2 * q) ^ m7) * 4)];
        bf16x8 pb1 = *(const bf16x8*)&sp[r15 * 64 + (((8 + 2 * q) ^ m7) * 4)];
#pragma unroll
        for (int mm = 0; mm < 4; mm++)
          acc3[mm] = __builtin_amdgcn_mfma_f32_16x16x32_bf16(
              mfA[mm], pb0, acc3[mm], 0, 0, 0);
#pragma unroll
        for (int mm = 0; mm < 4; mm++)
          mfA[mm] = *(const bf16x8*)(mtf +
              ((size_t)((b * 8 + h) * 8 + mm) * 2 + 1) * 512 + l * 8);
#pragma unroll
        for (int mm = 0; mm < 4; mm++)
          acc3[4 + mm] = __builtin_amdgcn_mfma_f32_16x16x32_bf16(
              mfB[mm], pb0, acc3[4 + mm], 0, 0, 0);
#pragma unroll
        for (int mm = 0; mm < 4; mm++)
          mfB[mm] = *(const bf16x8*)(mtf +
              ((size_t)((b * 8 + h) * 8 + 4 + mm) * 2 + 1) * 512 + l * 8);
#pragma unroll
        for (int mm = 0; mm < 4; mm++)
          acc3[mm] = __builtin_amdgcn_mfma_f32_16x16x32_bf16(
              mfA[mm], pb1, acc3[mm], 0, 0, 0);
#pragma unroll
        for (int mm = 0; mm < 4; mm++)
          acc3[4 + mm] = __builtin_amdgcn_mfma_f32_16x16x32_bf16(
              mfB[mm], pb1, acc3[4 + mm], 0, 0, 0);
      }
#pragma unroll
      for (int mi = 0; mi < 8; mi++){
        float4 bv = *(const float4*)(bo + 16 * mi + 4 * q);
        float bs[4] = {bv.x, bv.y, bv.z, bv.w};
#pragma unroll
        for (int r = 0; r < 4; r++){
          int c = 16 * mi + 4 * q + r;
          out[(size_t)(b * 128 + c) * N_ + t] = acc3[mi][r] + bs[r];
        }
      }
    }
  }
}

// ===========================================================================
// FALLBACK kernels (R8 file verbatim) — used only if cooperative launch
// is unavailable. See R7/R8 measurements.
// ===========================================================================
__global__ __launch_bounds__(256) void pconvx(const float* __restrict__ x,
    u16* __restrict__ xt, const float* __restrict__ Wq,
    const float* __restrict__ bq, const float* __restrict__ Wk,
    const float* __restrict__ bk, const float* __restrict__ Wv,
    const float* __restrict__ bv, u16* __restrict__ wkvf, u16* __restrict__ wqf,
    float* __restrict__ bkv, float* __restrict__ bqs){
  const int tid = threadIdx.x;
  const int bid = blockIdx.x;
  if (bid < 512){
    const int b = bid >> 7;
    const int kq = tid >> 6;
    const int t0 = (bid & 127) * 128 + 2 * (tid & 63);
    const float* xp = x + (size_t)(b * 128 + kq * 32) * N_ + t0;
    u16* dst = xt + (size_t)(b * N_ + t0) * 128;
#pragma unroll
    for (int gi = 0; gi < 4; gi++){
      float2 v[8];
#pragma unroll
      for (int j = 0; j < 8; j++)
        v[j] = *(const float2*)(xp + (size_t)(gi * 8 + j) * N_);
      const int g = kq * 4 + gi;
      {
        uint4 o;
        o.x = cvtpk(v[0].x, v[1].x); o.y = cvtpk(v[2].x, v[3].x);
        o.z = cvtpk(v[4].x, v[5].x); o.w = cvtpk(v[6].x, v[7].x);
        *(uint4*)(dst + ((g ^ (t0 & 15)) * 8)) = o;
      }
      {
        uint4 o;
        o.x = cvtpk(v[0].y, v[1].y); o.y = cvtpk(v[2].y, v[3].y);
        o.z = cvtpk(v[4].y, v[5].y); o.w = cvtpk(v[6].y, v[7].y);
        const int t = t0 + 1;
        *(uint4*)(dst + 128 + ((g ^ (t & 15)) * 8)) = o;
      }
    }
    return;
  }
  const int T = (bid - 512) * 256 + tid;
  if (T < 1024){
    int jj = T & 127, h = T >> 7;
    bkv[T] = (jj < 64) ? SCALE * bk[h * 64 + jj] : bv[h * 64 + jj - 64];
  } else if (T < 1536){
    bqs[T - 1024] = SCALE * bq[T - 1024];
  }
  const float* src; float sc; u16* dst;
  if (T < 16384){
    int l = T & 63, f = T >> 6;
    int ks = f & 3, jt = (f >> 2) & 7, h = f >> 5;
    int jj = 16 * jt + (l & 15);
    int k0 = ks * 32 + (l >> 4) * 8;
    if (jj < 64){ src = Wk + (size_t)(h * 64 + jj) * 128 + k0; sc = SCALE; }
    else        { src = Wv + (size_t)(h * 64 + jj - 64) * 128 + k0; sc = 1.f; }
    dst = wkvf + (size_t)f * 512 + l * 8;
  } else {
    int T2 = T - 16384;
    int l = T2 & 63, f = T2 >> 6;
    int ks = f & 3, dt = (f >> 2) & 3, h = f >> 4;
    int d = 16 * dt + (l & 15);
    int k0 = ks * 32 + (l >> 4) * 8;
    src = Wq + (size_t)(h * 64 + d) * 128 + k0; sc = SCALE;
    dst = wqf + (size_t)f * 512 + l * 8;
  }
  float4 a = *(const float4*)src, c = *(const float4*)(src + 4);
  ushort4 o0, o1;
  o0.x = f2bf(sc * a.x); o0.y = f2bf(sc * a.y); o0.z = f2bf(sc * a.z); o0.w = f2bf(sc * a.w);
  o1.x = f2bf(sc * c.x); o1.y = f2bf(sc * c.y); o1.z = f2bf(sc * c.z); o1.w = f2bf(sc * c.w);
  *(ushort4*)dst = o0; *(ushort4*)(dst + 4) = o1;
}

__global__ __launch_bounds__(256, 2) void kvctx(const u16* __restrict__ xt,
    const u16* __restrict__ wkvf, const float* __restrict__ bkv,
    float* __restrict__ pctx, float* __restrict__ prs){
  __shared__ u16 smem[32768];
  const int tid = threadIdx.x;
  const int chunk = blockIdx.x, h = blockIdx.y, b = blockIdx.z;
  const int w = tid >> 6, l = tid & 63, r15 = l & 15, q = l >> 4;
  const int th = w & 1, jh = w >> 1;

  bf16x8 wf[4][4];
#pragma unroll
  for (int ni = 0; ni < 4; ni++)
#pragma unroll
    for (int ks = 0; ks < 4; ks++)
      wf[ni][ks] = *(const bf16x8*)(wkvf +
          (size_t)((h * 8 + 4 * jh + ni) * 4 + ks) * 512 + l * 8);
  float barr[4];
#pragma unroll
  for (int ni = 0; ni < 4; ni++)
    barr[ni] = bkv[h * 128 + jh * 64 + 16 * ni + r15];

  const size_t tok0 = (size_t)b * N_ + chunk * 512;
  const char* gbase = (const char*)(xt + tok0 * 128);
  u16* sekv = smem + 16384;

#define STAGE(sub_)                                                            \
  {                                                                            \
    const char* gs = gbase + (size_t)(sub_)*32768 + w * 8192 + l * 16;         \
    char* ls = (char*)smem + w * 8192;                                         \
    _Pragma("unroll")                                                          \
    for (int p = 0; p < 8; p++)                                                \
      __builtin_amdgcn_global_load_lds(                                        \
          (const __attribute__((address_space(1))) void*)(gs + p * 1024),      \
          (__attribute__((address_space(3))) void*)(ls + p * 1024), 16, 0, 0); \
  }

  STAGE(0);
  __syncthreads();

  f32x4 acc2[4][4] = {};
  float rs[4] = {0.f, 0.f, 0.f, 0.f};

  for (int sub = 0; sub < 4; sub++){
    f32x4 acc1[4][4] = {};
#pragma unroll
    for (int ks = 0; ks < 4; ks++){
      bf16x8 xa[4];
#pragma unroll
      for (int mi = 0; mi < 4; mi++){
        int t = th * 64 + 16 * mi + r15;
        xa[mi] = *(const bf16x8*)&smem[t * 128 + (((ks * 4 + q) ^ r15) * 8)];
      }
#pragma unroll
      for (int mi = 0; mi < 4; mi++)
#pragma unroll
        for (int ni = 0; ni < 4; ni++)
          acc1[mi][ni] = __builtin_amdgcn_mfma_f32_16x16x32_bf16(
              xa[mi], wf[ni][ks], acc1[mi][ni], 0, 0, 0);
    }
    asm volatile("s_waitcnt lgkmcnt(0)" ::: "memory");
    __builtin_amdgcn_s_barrier();
    if (sub < 3) STAGE(sub + 1);
#pragma unroll
    for (int ni = 0; ni < 4; ni++){
      const float bb = barr[ni];
      const int j = jh * 64 + 16 * ni + r15;
      float ps = 0.f;
#pragma unroll
      for (int mi = 0; mi < 4; mi++){
        float vals[4];
#pragma unroll
        for (int r = 0; r < 4; r++) vals[r] = acc1[mi][ni][r] + bb;
        if (jh == 0){
#pragma unroll
          for (int r = 0; r < 4; r++){ vals[r] = __expf(vals[r]); ps += vals[r]; }
        }
        uint2 pk;
        pk.x = cvtpk(vals[0], vals[1]);
        pk.y = cvtpk(vals[2], vals[3]);
        int g8 = 16 * th + 4 * mi + q;
        int g8s = g8 ^ (2 * r15);
        *(uint2*)&sekv[j * 128 + g8s * 4] = pk;
      }
      if (jh == 0){
        ps += __shfl_xor(ps, 16); ps += __shfl_xor(ps, 32);
        rs[ni] += ps;
      }
    }
    asm volatile("s_waitcnt lgkmcnt(0)" ::: "memory");
    __builtin_amdgcn_s_barrier();
    {
      bf16x8 ka[4], va[4];
      const int g8s = (8 * w + 2 * q) ^ (2 * r15);
#pragma unroll
      for (int mi2 = 0; mi2 < 4; mi2++){
        int d = 16 * mi2 + r15;
        ka[mi2] = *(const bf16x8*)&sekv[d * 128 + g8s * 4];
      }
#pragma unroll
      for (int ni2 = 0; ni2 < 4; ni2++){
        int e = 16 * ni2 + r15;
        va[ni2] = *(const bf16x8*)&sekv[(64 + e) * 128 + g8s * 4];
      }
#pragma unroll
      for (int mi2 = 0; mi2 < 4; mi2++)
#pragma unroll
        for (int ni2 = 0; ni2 < 4; ni2++)
          acc2[mi2][ni2] = __builtin_amdgcn_mfma_f32_16x16x32_bf16(
              ka[mi2], va[ni2], acc2[mi2][ni2], 0, 0, 0);
    }
    __syncthreads();
  }
#undef STAGE
  float* fb = (float*)smem;
#pragma unroll
  for (int mi2 = 0; mi2 < 4; mi2++)
#pragma unroll
    for (int ni2 = 0; ni2 < 4; ni2++)
#pragma unroll
      for (int r = 0; r < 4; r++){
        int d = 16 * mi2 + 4 * q + r, e = 16 * ni2 + r15;
        fb[w * 4096 + d * 64 + e] = acc2[mi2][ni2][r];
      }
  __syncthreads();
  {
    float* dst = pctx + ((size_t)((b * 8 + h) * 32 + chunk)) * 4096 + tid * 16;
#pragma unroll
    for (int i = 0; i < 4; i++){
      int o = tid * 16 + 4 * i;
      float4 a = *(const float4*)(fb + o);
      float4 c = *(const float4*)(fb + 4096 + o);
      float4 d = *(const float4*)(fb + 8192 + o);
      float4 e = *(const float4*)(fb + 12288 + o);
      float4 s;
      s.x = a.x + c.x + d.x + e.x; s.y = a.y + c.y + d.y + e.y;
      s.z = a.z + c.z + d.z + e.z; s.w = a.w + c.w + d.w + e.w;
      *(float4*)(dst + 4 * i) = s;
    }
  }
  if (jh == 0 && q == 0){
    float* rb = prs + ((size_t)((b * 8 + h) * 32 + chunk)) * 128 + th * 64;
#pragma unroll
    for (int ni = 0; ni < 4; ni++) rb[16 * ni + r15] = rs[ni];
  }
}

__global__ __launch_bounds__(256) void redmker(const float* __restrict__ pctx,
    const float* __restrict__ prs, const float* __restrict__ Wo,
    u16* __restrict__ mtf){
  __shared__ float ctxh8[8][68];
  __shared__ float woht[64][132];
  __shared__ float rsh[8];
  const int tid = threadIdx.x;
  const int bh = blockIdx.x, s = blockIdx.y;
  const int h = bh & 7;
  {
    const int e4 = tid & 15, r0 = tid >> 4;
#pragma unroll
    for (int p = 0; p < 8; p++){
      int c = r0 + p * 16;
      float4 v = *(const float4*)(Wo + (size_t)c * 512 + h * 64 + 4 * e4);
      woht[4 * e4 + 0][c] = v.x; woht[4 * e4 + 1][c] = v.y;
      woht[4 * e4 + 2][c] = v.z; woht[4 * e4 + 3][c] = v.w;
    }
  }
  {
    const float* base = pctx + (size_t)bh * 131072 + s * 512 + tid * 2;
    float2 a = {0.f, 0.f};
#pragma unroll 4
    for (int c = 0; c < 32; c++){
      float2 v = *(const float2*)(base + c * 4096);
      a.x += v.x; a.y += v.y;
    }
    const int i = tid * 2;
    ctxh8[i >> 6][i & 63] = a.x;
    ctxh8[(i + 1) >> 6][(i + 1) & 63] = a.y;
  }
  {
    const int dl = tid >> 5, c = tid & 31;
    const int dg = s * 8 + dl;
    const float* rb = prs + (size_t)bh * 4096 + c * 128;
    float v = rb[dg] + rb[64 + dg];
    v += __shfl_xor(v, 1);  v += __shfl_xor(v, 2);
    v += __shfl_xor(v, 4);  v += __shfl_xor(v, 8);
    v += __shfl_xor(v, 16);
    if (c == 0) rsh[dl] = v;
  }
  __syncthreads();
  const int dl = tid >> 5, c0 = (tid & 31) * 4;
  const int d = s * 8 + dl;
  const float inv = 1.f / rsh[dl];
  float acc[4] = {0.f, 0.f, 0.f, 0.f};
  for (int e = 0; e < 64; e++){
    float cv = ctxh8[dl][e];
#pragma unroll
    for (int j = 0; j < 4; j++) acc[j] += cv * woht[e][c0 + j];
  }
  const int ks = d >> 5, lq = ((d >> 3) & 3) << 4, el = d & 7;
#pragma unroll
  for (int j = 0; j < 4; j++){
    int c = c0 + j;
    mtf[((size_t)(bh * 8 + (c >> 4)) * 2 + ks) * 512 + ((c & 15) | lq) * 8 + el]
        = f2bf(inv * acc[j]);
  }
}

__global__ __launch_bounds__(256, 3) void qout(const u16* __restrict__ xt,
    const u16* __restrict__ wqf, const float* __restrict__ bqs,
    const u16* __restrict__ mtf, const float* __restrict__ bo,
    float* __restrict__ out){
  __shared__ u16 smP[4][16 * 64];
  const int tid = threadIdx.x;
  const int tt = blockIdx.x, b = blockIdx.y;
  const int w = tid >> 6, l = tid & 63, r15 = l & 15, q = l >> 4;
  const int t0 = tt * 64;
  const int m7 = 2 * (r15 & 7);
  const int t = t0 + w * 16 + r15;

  bf16x8 xb[4];
#pragma unroll
  for (int ks = 0; ks < 4; ks++)
    xb[ks] = *(const bf16x8*)(xt + (size_t)(b * N_ + t) * 128 +
                              (((ks * 4 + q) ^ r15) * 8));

  u16* sp = smP[w];
  f32x4 acc3[8] = {};
  for (int h = 0; h < 8; h++){
    float bq_[4][4];
#pragma unroll
    for (int mi = 0; mi < 4; mi++){
      float4 v = *(const float4*)(bqs + h * 64 + 16 * mi + 4 * q);
      bq_[mi][0] = v.x; bq_[mi][1] = v.y; bq_[mi][2] = v.z; bq_[mi][3] = v.w;
    }
    f32x4 acc1[4] = {};
#pragma unroll
    for (int ks = 0; ks < 4; ks++){
      bf16x8 wqv[4];
#pragma unroll
      for (int mi = 0; mi < 4; mi++)
        wqv[mi] = *(const bf16x8*)(wqf +
            (size_t)((h * 4 + mi) * 4 + ks) * 512 + l * 8);
#pragma unroll
      for (int mi = 0; mi < 4; mi++)
        acc1[mi] = __builtin_amdgcn_mfma_f32_16x16x32_bf16(
            wqv[mi], xb[ks], acc1[mi], 0, 0, 0);
    }
    bf16x8 mfA[4], mfB[4];
#pragma unroll
    for (int mm = 0; mm < 4; mm++)
      mfA[mm] = *(const bf16x8*)(mtf +
          ((size_t)((b * 8 + h) * 8 + mm) * 2 + 0) * 512 + l * 8);
#pragma unroll
    for (int mm = 0; mm < 4; mm++)
      mfB[mm] = *(const bf16x8*)(mtf +
          ((size_t)((b * 8 + h) * 8 + 4 + mm) * 2 + 0) * 512 + l * 8);
    {
      float ps = 0.f;
#pragma unroll
      for (int mi = 0; mi < 4; mi++)
#pragma unroll
        for (int r = 0; r < 4; r++){
          float e = __expf(acc1[mi][r] + bq_[mi][r]);
          acc1[mi][r] = e; ps += e;
        }
      ps += __shfl_xor(ps, 16); ps += __shfl_xor(ps, 32);
      const float ci = 1.f / ps;
#pragma unroll
      for (int mi = 0; mi < 4; mi++){
        uint2 pk;
        pk.x = cvtpk(acc1[mi][0] * ci, acc1[mi][1] * ci);
        pk.y = cvtpk(acc1[mi][2] * ci, acc1[mi][3] * ci);
        int g8s = (4 * mi + q) ^ m7;
        *(uint2*)&sp[r15 * 64 + g8s * 4] = pk;
      }
    }
    bf16x8 pb0 = *(const bf16x8*)&sp[r15 * 64 + (((2 * q) ^ m7) * 4)];
    bf16x8 pb1 = *(const bf16x8*)&sp[r15 * 64 + (((8 + 2 * q) ^ m7) * 4)];
#pragma unroll
    for (int mm = 0; mm < 4; mm++)
      acc3[mm] = __builtin_amdgcn_mfma_f32_16x16x32_bf16(
          mfA[mm], pb0, acc3[mm], 0, 0, 0);
#pragma unroll
    for (int mm = 0; mm < 4; mm++)
      mfA[mm] = *(const bf16x8*)(mtf +
          ((size_t)((b * 8 + h) * 8 + mm) * 2 + 1) * 512 + l * 8);
#pragma unroll
    for (int mm = 0; mm < 4; mm++)
      acc3[4 + mm] = __builtin_amdgcn_mfma_f32_16x16x32_bf16(
          mfB[mm], pb0, acc3[4 + mm], 0, 0, 0);
#pragma unroll
    for (int mm = 0; mm < 4; mm++)
      mfB[mm] = *(const bf16x8*)(mtf +
          ((size_t)((b * 8 + h) * 8 + 4 + mm) * 2 + 1) * 512 + l * 8);
#pragma unroll
    for (int mm = 0; mm < 4; mm++)
      acc3[mm] = __builtin_amdgcn_mfma_f32_16x16x32_bf16(
          mfA[mm], pb1, acc3[mm], 0, 0, 0);
#pragma unroll
    for (int mm = 0; mm < 4; mm++)
      acc3[4 + mm] = __builtin_amdgcn_mfma_f32_16x16x32_bf16(
          mfB[mm], pb1, acc3[4 + mm], 0, 0, 0);
  }
#pragma unroll
  for (int mi = 0; mi < 8; mi++){
    float4 bv = *(const float4*)(bo + 16 * mi + 4 * q);
    float bs[4] = {bv.x, bv.y, bv.z, bv.w};
#pragma unroll
    for (int r = 0; r < 4; r++){
      int c = 16 * mi + 4 * q + r;
      out[(size_t)(b * 128 + c) * N_ + t] = acc3[mi][r] + bs[r];
    }
  }
}

// ---------------------------------------------------------------------------
extern "C" void kernel_launch(void* const* d_in, const int* in_sizes, int n_in,
                              void* d_out, int out_size, void* d_ws, size_t ws_size,
                              hipStream_t stream){
  const float* x  = (const float*)d_in[0];
  const float* Wq = (const float*)d_in[1];
  const float* bq = (const float*)d_in[2];
  const float* Wk = (const float*)d_in[3];
  const float* bk = (const float*)d_in[4];
  const float* Wv = (const float*)d_in[5];
  const float* bv = (const float*)d_in[6];
  const float* Wo = (const float*)d_in[7];
  const float* bo = (const float*)d_in[8];
  float* out = (float*)d_out;

  char* ws = (char*)d_ws;
  u16*   xt     = (u16*)ws;                         // 16 MiB (pre-swizzled)
  u16*   wkvf   = (u16*)(ws + 16777216);            // 256 KiB
  u16*   wqf    = (u16*)(ws + 17039360);            // 128 KiB
  u16*   mtf    = (u16*)(ws + 17170432);            // 512 KiB
  float* bkv    = (float*)(ws + 17694720);          // 4 KiB
  float* bqs    = (float*)(ws + 17698816);          // 2 KiB
  float* pctx   = (float*)(ws + 18233344);          // 16 MiB
  float* prs    = (float*)(ws + 35010560);          // 512 KiB

  void* args[] = {
    (void*)&x, (void*)&Wq, (void*)&bq, (void*)&Wk, (void*)&bk,
    (void*)&Wv, (void*)&bv, (void*)&Wo, (void*)&bo, (void*)&out,
    (void*)&xt, (void*)&wkvf, (void*)&wqf, (void*)&mtf,
    (void*)&bkv, (void*)&bqs, (void*)&pctx, (void*)&prs
  };
  hipError_t err = hipLaunchCooperativeKernel(
      (void*)fused, dim3(512), dim3(256), args, 0, stream);
  if (err != hipSuccess){
    // fallback: proven 4-kernel path (R7/R8)
    pconvx <<<608, 256, 0, stream>>>(x, xt, Wq, bq, Wk, bk, Wv, bv,
                                     wkvf, wqf, bkv, bqs);
    kvctx  <<<dim3(32, 8, 4), 256, 0, stream>>>(xt, wkvf, bkv, pctx, prs);
    redmker<<<dim3(32, 8), 256, 0, stream>>>(pctx, prs, Wo, mtf);
    qout   <<<dim3(256, 4), 256, 0, stream>>>(xt, wqf, bqs, mtf, bo, out);
  }
}

// Round 10
// 221.164 us; speedup vs baseline: 2.6706x; 2.6706x over previous
//
#include <hip/hip_runtime.h>

typedef unsigned short u16;
typedef __bf16 bf16x8 __attribute__((ext_vector_type(8)));
typedef float f32x4 __attribute__((ext_vector_type(4)));

#define N_ 16384
#define SCALE 0.35355339059327379f   // 64^-0.25

__device__ __forceinline__ u16 f2bf(float f){
  union { float f; unsigned int i; } v; v.f = f;
  unsigned int b = v.i;
  return (u16)((b + 0x7FFFu + ((b >> 16) & 1u)) >> 16);
}
// packed RNE f32x2 -> bf16x2 (bit-identical to f2bf pair, 1 instr)
__device__ __forceinline__ unsigned int cvtpk(float a, float b){
  unsigned int r;
  asm("v_cvt_pk_bf16_f32 %0, %1, %2" : "=v"(r) : "v"(a), "v"(b));
  return r;
}

// ---------------------------------------------------------------------------
// pconvx = prep + convx fused (R7-proven, unchanged).
// ---------------------------------------------------------------------------
__global__ __launch_bounds__(256) void pconvx(const float* __restrict__ x,
    u16* __restrict__ xt, const float* __restrict__ Wq,
    const float* __restrict__ bq, const float* __restrict__ Wk,
    const float* __restrict__ bk, const float* __restrict__ Wv,
    const float* __restrict__ bv, u16* __restrict__ wkvf, u16* __restrict__ wqf,
    float* __restrict__ bkv, float* __restrict__ bqs){
  const int tid = threadIdx.x;
  const int bid = blockIdx.x;
  if (bid < 512){
    const int b = bid >> 7;
    const int kq = tid >> 6;                           // wave = k-quarter
    const int t0 = (bid & 127) * 128 + 2 * (tid & 63); // 2 tokens / thread
    const float* xp = x + (size_t)(b * 128 + kq * 32) * N_ + t0;
    u16* dst = xt + (size_t)(b * N_ + t0) * 128;
#pragma unroll
    for (int gi = 0; gi < 4; gi++){
      float2 v[8];
#pragma unroll
      for (int j = 0; j < 8; j++)
        v[j] = *(const float2*)(xp + (size_t)(gi * 8 + j) * N_);
      const int g = kq * 4 + gi;
      {
        uint4 o;
        o.x = cvtpk(v[0].x, v[1].x); o.y = cvtpk(v[2].x, v[3].x);
        o.z = cvtpk(v[4].x, v[5].x); o.w = cvtpk(v[6].x, v[7].x);
        *(uint4*)(dst + ((g ^ (t0 & 15)) * 8)) = o;
      }
      {
        uint4 o;
        o.x = cvtpk(v[0].y, v[1].y); o.y = cvtpk(v[2].y, v[3].y);
        o.z = cvtpk(v[4].y, v[5].y); o.w = cvtpk(v[6].y, v[7].y);
        const int t = t0 + 1;
        *(uint4*)(dst + 128 + ((g ^ (t & 15)) * 8)) = o;
      }
    }
    return;
  }
  // ---- prep path ----
  const int T = (bid - 512) * 256 + tid;   // 0..24575
  if (T < 1024){
    int jj = T & 127, h = T >> 7;
    bkv[T] = (jj < 64) ? SCALE * bk[h * 64 + jj] : bv[h * 64 + jj - 64];
  } else if (T < 1536){
    bqs[T - 1024] = SCALE * bq[T - 1024];
  }
  const float* src; float sc; u16* dst;
  if (T < 16384){
    int l = T & 63, f = T >> 6;
    int ks = f & 3, jt = (f >> 2) & 7, h = f >> 5;
    int jj = 16 * jt + (l & 15);
    int k0 = ks * 32 + (l >> 4) * 8;
    if (jj < 64){ src = Wk + (size_t)(h * 64 + jj) * 128 + k0; sc = SCALE; }
    else        { src = Wv + (size_t)(h * 64 + jj - 64) * 128 + k0; sc = 1.f; }
    dst = wkvf + (size_t)f * 512 + l * 8;
  } else {
    int T2 = T - 16384;
    int l = T2 & 63, f = T2 >> 6;
    int ks = f & 3, dt = (f >> 2) & 3, h = f >> 4;
    int d = 16 * dt + (l & 15);
    int k0 = ks * 32 + (l >> 4) * 8;
    src = Wq + (size_t)(h * 64 + d) * 128 + k0; sc = SCALE;
    dst = wqf + (size_t)f * 512 + l * 8;
  }
  float4 a = *(const float4*)src, c = *(const float4*)(src + 4);
  ushort4 o0, o1;
  o0.x = f2bf(sc * a.x); o0.y = f2bf(sc * a.y); o0.z = f2bf(sc * a.z); o0.w = f2bf(sc * a.w);
  o1.x = f2bf(sc * c.x); o1.y = f2bf(sc * c.y); o1.z = f2bf(sc * c.z); o1.w = f2bf(sc * c.w);
  *(ushort4*)dst = o0; *(ushort4*)(dst + 4) = o1;
}

// ---------------------------------------------------------------------------
// kvctx v7: 64-token subs (8x). LDS 32 KiB (sx 16K + sekv 16K) -> 4 blocks/CU,
// 16 waves/CU (was 2 blocks, 8 waves). MFMA2 output-split: wave owns 32x32
// output tile over FULL token-K (acc2 16 VGPR, no fb reduction, direct pctx
// store). wf frags reloaded per sub from L2 (transient regs). Token-ascending
// MFMA accumulation order preserved.
// ---------------------------------------------------------------------------
__global__ __launch_bounds__(256, 4) void kvctx(const u16* __restrict__ xt,
    const u16* __restrict__ wkvf, const float* __restrict__ bkv,
    float* __restrict__ pctx, float* __restrict__ prs){
  __shared__ u16 smem[16384];   // sx bytes [0,16384) ; sekv bytes [16384,32768)
  const int tid = threadIdx.x;
  const int chunk = blockIdx.x, h = blockIdx.y, b = blockIdx.z;
  const int w = tid >> 6, l = tid & 63, r15 = l & 15, q = l >> 4;
  const int th = w & 1, jh = w >> 1;   // MFMA1/exp roles
  const int dw = w & 1, ew = w >> 1;   // MFMA2 output-tile assignment
  const int sw = r15 & 14;             // even swizzle (preserves 16B pairs)

  float barr[4];
#pragma unroll
  for (int ni = 0; ni < 4; ni++)
    barr[ni] = bkv[h * 128 + jh * 64 + 16 * ni + r15];

  const size_t tok0 = (size_t)b * N_ + chunk * 512;
  const char* gbase = (const char*)(xt + tok0 * 128);  // 512 rows x 256 B
  u16* sekv = smem + 8192;             // u16 offset (byte 16384)

  // async stage of 16-KiB x sub-tile: wave w copies bytes [4096w, 4096w+4096)
#define STAGE(sub_)                                                            \
  {                                                                            \
    const char* gs = gbase + (size_t)(sub_)*16384 + w * 4096 + l * 16;         \
    char* ls = (char*)smem + w * 4096;                                         \
    _Pragma("unroll")                                                          \
    for (int p = 0; p < 4; p++)                                                \
      __builtin_amdgcn_global_load_lds(                                        \
          (const __attribute__((address_space(1))) void*)(gs + p * 1024),      \
          (__attribute__((address_space(3))) void*)(ls + p * 1024), 16, 0, 0); \
  }

  STAGE(0);
  __syncthreads();   // sub0 x-tile ready

  f32x4 acc2[2][2] = {};
  float rs[4] = {0.f, 0.f, 0.f, 0.f};

  for (int sub = 0; sub < 8; sub++){
    // MFMA1: D[t 64][j 128], K=128 channels; wf reloaded per sub (L2-hot)
    f32x4 acc1[2][4] = {};
#pragma unroll
    for (int ks = 0; ks < 4; ks++){
      bf16x8 wfv[4];
#pragma unroll
      for (int ni = 0; ni < 4; ni++)
        wfv[ni] = *(const bf16x8*)(wkvf +
            (size_t)((h * 8 + 4 * jh + ni) * 4 + ks) * 512 + l * 8);
      bf16x8 xa[2];
#pragma unroll
      for (int mi = 0; mi < 2; mi++){
        int t = th * 32 + 16 * mi + r15;
        xa[mi] = *(const bf16x8*)&smem[t * 128 + (((ks * 4 + q) ^ r15) * 8)];
      }
#pragma unroll
      for (int mi = 0; mi < 2; mi++)
#pragma unroll
        for (int ni = 0; ni < 4; ni++)
          acc1[mi][ni] = __builtin_amdgcn_mfma_f32_16x16x32_bf16(
              xa[mi], wfv[ni], acc1[mi][ni], 0, 0, 0);
    }
    // B0 (lgkm-only): all waves done READING sx -> safe to overwrite
    asm volatile("s_waitcnt lgkmcnt(0)" ::: "memory");
    __builtin_amdgcn_s_barrier();
    if (sub < 7) STAGE(sub + 1);   // flies under exp + MFMA2
#pragma unroll
    for (int ni = 0; ni < 4; ni++){
      const float bb = barr[ni];
      const int j = jh * 64 + 16 * ni + r15;
      float ps = 0.f;
#pragma unroll
      for (int mi = 0; mi < 2; mi++){
        float vals[4];
#pragma unroll
        for (int r = 0; r < 4; r++) vals[r] = acc1[mi][ni][r] + bb;
        if (jh == 0){
#pragma unroll
          for (int r = 0; r < 4; r++){ vals[r] = __expf(vals[r]); ps += vals[r]; }
        }
        uint2 pk;
        pk.x = cvtpk(vals[0], vals[1]);
        pk.y = cvtpk(vals[2], vals[3]);
        int g8 = 8 * th + 4 * mi + q;      // 4-token group 0..15
        int g8s = g8 ^ sw;                 // conflict-free, pair-preserving
        *(uint2*)&sekv[j * 64 + g8s * 4] = pk;
      }
      if (jh == 0){
        ps += __shfl_xor(ps, 16); ps += __shfl_xor(ps, 32);
        rs[ni] += ps;
      }
    }
    // B1 (lgkm-only): sekv writes visible; staging vmcnt NOT drained
    asm volatile("s_waitcnt lgkmcnt(0)" ::: "memory");
    __builtin_amdgcn_s_barrier();
    // MFMA2: wave owns output (32dw..32dw+31) x (32ew..32ew+31), full K
#pragma unroll
    for (int ks2 = 0; ks2 < 2; ks2++){
      const int gr = ((8 * ks2 + 2 * q) ^ sw) * 4;   // u16 offset (16B aligned)
      bf16x8 ka0 = *(const bf16x8*)&sekv[(32 * dw + r15) * 64 + gr];
      bf16x8 ka1 = *(const bf16x8*)&sekv[(32 * dw + 16 + r15) * 64 + gr];
      bf16x8 va0 = *(const bf16x8*)&sekv[(64 + 32 * ew + r15) * 64 + gr];
      bf16x8 va1 = *(const bf16x8*)&sekv[(64 + 32 * ew + 16 + r15) * 64 + gr];
      acc2[0][0] = __builtin_amdgcn_mfma_f32_16x16x32_bf16(ka0, va0, acc2[0][0], 0, 0, 0);
      acc2[0][1] = __builtin_amdgcn_mfma_f32_16x16x32_bf16(ka0, va1, acc2[0][1], 0, 0, 0);
      acc2[1][0] = __builtin_amdgcn_mfma_f32_16x16x32_bf16(ka1, va0, acc2[1][0], 0, 0, 0);
      acc2[1][1] = __builtin_amdgcn_mfma_f32_16x16x32_bf16(ka1, va1, acc2[1][1], 0, 0, 0);
    }
    __syncthreads();   // B2 (full): staged sx ready; sekv consumed
  }
#undef STAGE
  // direct pctx store: each (d,e) owned by exactly one thread
  {
    float* dst = pctx + ((size_t)((b * 8 + h) * 32 + chunk)) * 4096;
#pragma unroll
    for (int df = 0; df < 2; df++)
#pragma unroll
      for (int ef = 0; ef < 2; ef++)
#pragma unroll
        for (int r = 0; r < 4; r++){
          int d = 32 * dw + 16 * df + 4 * q + r;
          int e = 32 * ew + 16 * ef + r15;
          dst[d * 64 + e] = acc2[df][ef][r];
        }
  }
  if (jh == 0 && q == 0){
    float* rb = prs + ((size_t)((b * 8 + h) * 32 + chunk)) * 128 + th * 64;
#pragma unroll
    for (int ni = 0; ni < 4; ni++) rb[16 * ni + r15] = rs[ni];
  }
}

// ---------------------------------------------------------------------------
// redmker v2 (R7-proven, unchanged): 256 blocks (32 bh x 8 d-slices).
// ---------------------------------------------------------------------------
__global__ __launch_bounds__(256) void redmker(const float* __restrict__ pctx,
    const float* __restrict__ prs, const float* __restrict__ Wo,
    u16* __restrict__ mtf){
  __shared__ float ctxh8[8][68];
  __shared__ float woht[64][132];
  __shared__ float rsh[8];
  const int tid = threadIdx.x;
  const int bh = blockIdx.x, s = blockIdx.y;
  const int h = bh & 7;
  { // stage Wo^T slice for head h
    const int e4 = tid & 15, r0 = tid >> 4;
#pragma unroll
    for (int p = 0; p < 8; p++){
      int c = r0 + p * 16;
      float4 v = *(const float4*)(Wo + (size_t)c * 512 + h * 64 + 4 * e4);
      woht[4 * e4 + 0][c] = v.x; woht[4 * e4 + 1][c] = v.y;
      woht[4 * e4 + 2][c] = v.z; woht[4 * e4 + 3][c] = v.w;
    }
  }
  { // reduce 32 chunk-partials of this 512-float slice (float2/thread)
    const float* base = pctx + (size_t)bh * 131072 + s * 512 + tid * 2;
    float2 a = {0.f, 0.f};
#pragma unroll 4
    for (int c = 0; c < 32; c++){
      float2 v = *(const float2*)(base + c * 4096);
      a.x += v.x; a.y += v.y;
    }
    const int i = tid * 2;
    ctxh8[i >> 6][i & 63] = a.x;
    ctxh8[(i + 1) >> 6][(i + 1) & 63] = a.y;
  }
  { // rowsum for the 8 d-rows of this slice
    const int dl = tid >> 5, c = tid & 31;
    const int dg = s * 8 + dl;
    const float* rb = prs + (size_t)bh * 4096 + c * 128;
    float v = rb[dg] + rb[64 + dg];
    v += __shfl_xor(v, 1);  v += __shfl_xor(v, 2);
    v += __shfl_xor(v, 4);  v += __shfl_xor(v, 8);
    v += __shfl_xor(v, 16);
    if (c == 0) rsh[dl] = v;
  }
  __syncthreads();
  const int dl = tid >> 5, c0 = (tid & 31) * 4;
  const int d = s * 8 + dl;
  const float inv = 1.f / rsh[dl];
  float acc[4] = {0.f, 0.f, 0.f, 0.f};
  for (int e = 0; e < 64; e++){
    float cv = ctxh8[dl][e];
#pragma unroll
    for (int j = 0; j < 4; j++) acc[j] += cv * woht[e][c0 + j];
  }
  const int ks = d >> 5, lq = ((d >> 3) & 3) << 4, el = d & 7;
#pragma unroll
  for (int j = 0; j < 4; j++){
    int c = c0 + j;
    mtf[((size_t)(bh * 8 + (c >> 4)) * 2 + ks) * 512 + ((c & 15) | lq) * 8 + el]
        = f2bf(inv * acc[j]);
  }
}

// ---------------------------------------------------------------------------
// qout v7 (R7-measured, unchanged): 64-token tiles, mf-prefetch + X/Y
// rotation in MFMA2.
// ---------------------------------------------------------------------------
__global__ __launch_bounds__(256, 3) void qout(const u16* __restrict__ xt,
    const u16* __restrict__ wqf, const float* __restrict__ bqs,
    const u16* __restrict__ mtf, const float* __restrict__ bo,
    float* __restrict__ out){
  __shared__ u16 smP[4][16 * 64]; // per-wave p[16t][64d]  (8 KiB total)
  const int tid = threadIdx.x;
  const int tt = blockIdx.x, b = blockIdx.y;
  const int w = tid >> 6, l = tid & 63, r15 = l & 15, q = l >> 4;
  const int t0 = tt * 64;
  const int m7 = 2 * (r15 & 7);
  const int t = t0 + w * 16 + r15;

  // x B-frags for this wave's 16 tokens (h-independent, pre-swizzled xt)
  bf16x8 xb[4];
#pragma unroll
  for (int ks = 0; ks < 4; ks++)
    xb[ks] = *(const bf16x8*)(xt + (size_t)(b * N_ + t) * 128 +
                              (((ks * 4 + q) ^ r15) * 8));

  u16* sp = smP[w];
  f32x4 acc3[8] = {};
  for (int h = 0; h < 8; h++){
    float bq_[4][4];
#pragma unroll
    for (int mi = 0; mi < 4; mi++){
      float4 v = *(const float4*)(bqs + h * 64 + 16 * mi + 4 * q);
      bq_[mi][0] = v.x; bq_[mi][1] = v.y; bq_[mi][2] = v.z; bq_[mi][3] = v.w;
    }
    // MFMA1: D[d 64][t 16], K=128; A = wq frags (L2), B = xb (regs)
    f32x4 acc1[4] = {};
#pragma unroll
    for (int ks = 0; ks < 4; ks++){
      bf16x8 wqv[4];
#pragma unroll
      for (int mi = 0; mi < 4; mi++)
        wqv[mi] = *(const bf16x8*)(wqf +
            (size_t)((h * 4 + mi) * 4 + ks) * 512 + l * 8);
#pragma unroll
      for (int mi = 0; mi < 4; mi++)
        acc1[mi] = __builtin_amdgcn_mfma_f32_16x16x32_bf16(
            wqv[mi], xb[ks], acc1[mi], 0, 0, 0);
    }
    // prefetch ks2=0 mf frags (independent of softmax)
    bf16x8 mfA[4], mfB[4];
#pragma unroll
    for (int mm = 0; mm < 4; mm++)
      mfA[mm] = *(const bf16x8*)(mtf +
          ((size_t)((b * 8 + h) * 8 + mm) * 2 + 0) * 512 + l * 8);
#pragma unroll
    for (int mm = 0; mm < 4; mm++)
      mfB[mm] = *(const bf16x8*)(mtf +
          ((size_t)((b * 8 + h) * 8 + 4 + mm) * 2 + 0) * 512 + l * 8);
    // exp + in-wave colsum + normalized p store (wave-private)
    {
      float ps = 0.f;
#pragma unroll
      for (int mi = 0; mi < 4; mi++)
#pragma unroll
        for (int r = 0; r < 4; r++){
          float e = __expf(acc1[mi][r] + bq_[mi][r]);
          acc1[mi][r] = e; ps += e;
        }
      ps += __shfl_xor(ps, 16); ps += __shfl_xor(ps, 32);
      const float ci = 1.f / ps;
#pragma unroll
      for (int mi = 0; mi < 4; mi++){
        uint2 pk;
        pk.x = cvtpk(acc1[mi][0] * ci, acc1[mi][1] * ci);
        pk.y = cvtpk(acc1[mi][2] * ci, acc1[mi][3] * ci);
        int g8s = (4 * mi + q) ^ m7;
        *(uint2*)&sp[r15 * 64 + g8s * 4] = pk;
      }
    }
    // MFMA2 with X/Y rotation: ks2=1 loads hide under MFMA batches
    bf16x8 pb0 = *(const bf16x8*)&sp[r15 * 64 + (((2 * q) ^ m7) * 4)];
    bf16x8 pb1 = *(const bf16x8*)&sp[r15 * 64 + (((8 + 2 * q) ^ m7) * 4)];
#pragma unroll
    for (int mm = 0; mm < 4; mm++)
      acc3[mm] = __builtin_amdgcn_mfma_f32_16x16x32_bf16(
          mfA[mm], pb0, acc3[mm], 0, 0, 0);
#pragma unroll
    for (int mm = 0; mm < 4; mm++)
      mfA[mm] = *(const bf16x8*)(mtf +
          ((size_t)((b * 8 + h) * 8 + mm) * 2 + 1) * 512 + l * 8);
#pragma unroll
    for (int mm = 0; mm < 4; mm++)
      acc3[4 + mm] = __builtin_amdgcn_mfma_f32_16x16x32_bf16(
          mfB[mm], pb0, acc3[4 + mm], 0, 0, 0);
#pragma unroll
    for (int mm = 0; mm < 4; mm++)
      mfB[mm] = *(const bf16x8*)(mtf +
          ((size_t)((b * 8 + h) * 8 + 4 + mm) * 2 + 1) * 512 + l * 8);
#pragma unroll
    for (int mm = 0; mm < 4; mm++)
      acc3[mm] = __builtin_amdgcn_mfma_f32_16x16x32_bf16(
          mfA[mm], pb1, acc3[mm], 0, 0, 0);
#pragma unroll
    for (int mm = 0; mm < 4; mm++)
      acc3[4 + mm] = __builtin_amdgcn_mfma_f32_16x16x32_bf16(
          mfB[mm], pb1, acc3[4 + mm], 0, 0, 0);
  }
#pragma unroll
  for (int mi = 0; mi < 8; mi++){
    float4 bv = *(const float4*)(bo + 16 * mi + 4 * q);
    float bs[4] = {bv.x, bv.y, bv.z, bv.w};
#pragma unroll
    for (int r = 0; r < 4; r++){
      int c = 16 * mi + 4 * q + r;
      out[(size_t)(b * 128 + c) * N_ + t] = acc3[mi][r] + bs[r];
    }
  }
}

// ---------------------------------------------------------------------------
extern "C" void kernel_launch(void* const* d_in, const int* in_sizes, int n_in,
                              void* d_out, int out_size, void* d_ws, size_t ws_size,
                              hipStream_t stream){
  const float* x  = (const float*)d_in[0];
  const float* Wq = (const float*)d_in[1];
  const float* bq = (const float*)d_in[2];
  const float* Wk = (const float*)d_in[3];
  const float* bk = (const float*)d_in[4];
  const float* Wv = (const float*)d_in[5];
  const float* bv = (const float*)d_in[6];
  const float* Wo = (const float*)d_in[7];
  const float* bo = (const float*)d_in[8];
  float* out = (float*)d_out;

  char* ws = (char*)d_ws;
  u16*   xt     = (u16*)ws;                         // 16 MiB (pre-swizzled)
  u16*   wkvf   = (u16*)(ws + 16777216);            // 256 KiB
  u16*   wqf    = (u16*)(ws + 17039360);            // 128 KiB
  u16*   mtf    = (u16*)(ws + 17170432);            // 512 KiB
  float* bkv    = (float*)(ws + 17694720);          // 4 KiB
  float* bqs    = (float*)(ws + 17698816);          // 2 KiB
  float* pctx   = (float*)(ws + 18233344);          // 16 MiB
  float* prs    = (float*)(ws + 35010560);          // 512 KiB

  pconvx <<<608, 256, 0, stream>>>(x, xt, Wq, bq, Wk, bk, Wv, bv,
                                   wkvf, wqf, bkv, bqs);
  kvctx  <<<dim3(32, 8, 4), 256, 0, stream>>>(xt, wkvf, bkv, pctx, prs);
  redmker<<<dim3(32, 8), 256, 0, stream>>>(pctx, prs, Wo, mtf);
  qout   <<<dim3(256, 4), 256, 0, stream>>>(xt, wqf, bqs, mtf, bo, out);
}

// Round 11
// 170.485 us; speedup vs baseline: 3.4645x; 1.2973x over previous
//
#include <hip/hip_runtime.h>

typedef unsigned short u16;
typedef __bf16 bf16x8 __attribute__((ext_vector_type(8)));
typedef float f32x4 __attribute__((ext_vector_type(4)));

#define N_ 16384
#define SCALE 0.35355339059327379f   // 64^-0.25

__device__ __forceinline__ u16 f2bf(float f){
  union { float f; unsigned int i; } v; v.f = f;
  unsigned int b = v.i;
  return (u16)((b + 0x7FFFu + ((b >> 16) & 1u)) >> 16);
}
// packed RNE f32x2 -> bf16x2 (bit-identical to f2bf pair, 1 instr)
__device__ __forceinline__ unsigned int cvtpk(float a, float b){
  unsigned int r;
  asm("v_cvt_pk_bf16_f32 %0, %1, %2" : "=v"(r) : "v"(a), "v"(b));
  return r;
}

// ---------------------------------------------------------------------------
// pconvx = prep + convx fused (R7-proven, unchanged).
// ---------------------------------------------------------------------------
__global__ __launch_bounds__(256) void pconvx(const float* __restrict__ x,
    u16* __restrict__ xt, const float* __restrict__ Wq,
    const float* __restrict__ bq, const float* __restrict__ Wk,
    const float* __restrict__ bk, const float* __restrict__ Wv,
    const float* __restrict__ bv, u16* __restrict__ wkvf, u16* __restrict__ wqf,
    float* __restrict__ bkv, float* __restrict__ bqs){
  const int tid = threadIdx.x;
  const int bid = blockIdx.x;
  if (bid < 512){
    const int b = bid >> 7;
    const int kq = tid >> 6;                           // wave = k-quarter
    const int t0 = (bid & 127) * 128 + 2 * (tid & 63); // 2 tokens / thread
    const float* xp = x + (size_t)(b * 128 + kq * 32) * N_ + t0;
    u16* dst = xt + (size_t)(b * N_ + t0) * 128;
#pragma unroll
    for (int gi = 0; gi < 4; gi++){
      float2 v[8];
#pragma unroll
      for (int j = 0; j < 8; j++)
        v[j] = *(const float2*)(xp + (size_t)(gi * 8 + j) * N_);
      const int g = kq * 4 + gi;
      {
        uint4 o;
        o.x = cvtpk(v[0].x, v[1].x); o.y = cvtpk(v[2].x, v[3].x);
        o.z = cvtpk(v[4].x, v[5].x); o.w = cvtpk(v[6].x, v[7].x);
        *(uint4*)(dst + ((g ^ (t0 & 15)) * 8)) = o;
      }
      {
        uint4 o;
        o.x = cvtpk(v[0].y, v[1].y); o.y = cvtpk(v[2].y, v[3].y);
        o.z = cvtpk(v[4].y, v[5].y); o.w = cvtpk(v[6].y, v[7].y);
        const int t = t0 + 1;
        *(uint4*)(dst + 128 + ((g ^ (t & 15)) * 8)) = o;
      }
    }
    return;
  }
  // ---- prep path ----
  const int T = (bid - 512) * 256 + tid;   // 0..24575
  if (T < 1024){
    int jj = T & 127, h = T >> 7;
    bkv[T] = (jj < 64) ? SCALE * bk[h * 64 + jj] : bv[h * 64 + jj - 64];
  } else if (T < 1536){
    bqs[T - 1024] = SCALE * bq[T - 1024];
  }
  const float* src; float sc; u16* dst;
  if (T < 16384){
    int l = T & 63, f = T >> 6;
    int ks = f & 3, jt = (f >> 2) & 7, h = f >> 5;
    int jj = 16 * jt + (l & 15);
    int k0 = ks * 32 + (l >> 4) * 8;
    if (jj < 64){ src = Wk + (size_t)(h * 64 + jj) * 128 + k0; sc = SCALE; }
    else        { src = Wv + (size_t)(h * 64 + jj - 64) * 128 + k0; sc = 1.f; }
    dst = wkvf + (size_t)f * 512 + l * 8;
  } else {
    int T2 = T - 16384;
    int l = T2 & 63, f = T2 >> 6;
    int ks = f & 3, dt = (f >> 2) & 3, h = f >> 4;
    int d = 16 * dt + (l & 15);
    int k0 = ks * 32 + (l >> 4) * 8;
    src = Wq + (size_t)(h * 64 + d) * 128 + k0; sc = SCALE;
    dst = wqf + (size_t)f * 512 + l * 8;
  }
  float4 a = *(const float4*)src, c = *(const float4*)(src + 4);
  ushort4 o0, o1;
  o0.x = f2bf(sc * a.x); o0.y = f2bf(sc * a.y); o0.z = f2bf(sc * a.z); o0.w = f2bf(sc * a.w);
  o1.x = f2bf(sc * c.x); o1.y = f2bf(sc * c.y); o1.z = f2bf(sc * c.z); o1.w = f2bf(sc * c.w);
  *(ushort4*)dst = o0; *(ushort4*)(dst + 4) = o1;
}

// ---------------------------------------------------------------------------
// kvctx (R4-proven, reverted verbatim): global_load_lds staging after
// lgkm-only B0; only B2 drains vmcnt. 2 blocks/CU, LDS-tiled epilogue.
// ---------------------------------------------------------------------------
__global__ __launch_bounds__(256, 2) void kvctx(const u16* __restrict__ xt,
    const u16* __restrict__ wkvf, const float* __restrict__ bkv,
    float* __restrict__ pctx, float* __restrict__ prs){
  __shared__ u16 smem[32768];   // sx [0,32768)B ; sekv [32768,65536)B ; fb overlay
  const int tid = threadIdx.x;
  const int chunk = blockIdx.x, h = blockIdx.y, b = blockIdx.z;
  const int w = tid >> 6, l = tid & 63, r15 = l & 15, q = l >> 4;
  const int th = w & 1, jh = w >> 1;

  bf16x8 wf[4][4];
#pragma unroll
  for (int ni = 0; ni < 4; ni++)
#pragma unroll
    for (int ks = 0; ks < 4; ks++)
      wf[ni][ks] = *(const bf16x8*)(wkvf +
          (size_t)((h * 8 + 4 * jh + ni) * 4 + ks) * 512 + l * 8);
  float barr[4];
#pragma unroll
  for (int ni = 0; ni < 4; ni++)
    barr[ni] = bkv[h * 128 + jh * 64 + 16 * ni + r15];

  const size_t tok0 = (size_t)b * N_ + chunk * 512;
  const char* gbase = (const char*)(xt + tok0 * 128);  // 512 rows x 256 B
  u16* sekv = smem + 16384;

#define STAGE(sub_)                                                            \
  {                                                                            \
    const char* gs = gbase + (size_t)(sub_)*32768 + w * 8192 + l * 16;         \
    char* ls = (char*)smem + w * 8192;                                         \
    _Pragma("unroll")                                                          \
    for (int p = 0; p < 8; p++)                                                \
      __builtin_amdgcn_global_load_lds(                                        \
          (const __attribute__((address_space(1))) void*)(gs + p * 1024),      \
          (__attribute__((address_space(3))) void*)(ls + p * 1024), 16, 0, 0); \
  }

  STAGE(0);
  __syncthreads();   // sub0 x-tile ready

  f32x4 acc2[4][4] = {};
  float rs[4] = {0.f, 0.f, 0.f, 0.f};

  for (int sub = 0; sub < 4; sub++){
    f32x4 acc1[4][4] = {};
#pragma unroll
    for (int ks = 0; ks < 4; ks++){
      bf16x8 xa[4];
#pragma unroll
      for (int mi = 0; mi < 4; mi++){
        int t = th * 64 + 16 * mi + r15;
        xa[mi] = *(const bf16x8*)&smem[t * 128 + (((ks * 4 + q) ^ r15) * 8)];
      }
#pragma unroll
      for (int mi = 0; mi < 4; mi++)
#pragma unroll
        for (int ni = 0; ni < 4; ni++)
          acc1[mi][ni] = __builtin_amdgcn_mfma_f32_16x16x32_bf16(
              xa[mi], wf[ni][ks], acc1[mi][ni], 0, 0, 0);
    }
    // B0 (lgkm-only): all waves done READING sx -> safe to overwrite
    asm volatile("s_waitcnt lgkmcnt(0)" ::: "memory");
    __builtin_amdgcn_s_barrier();
    if (sub < 3) STAGE(sub + 1);   // flies under softmax + MFMA2
#pragma unroll
    for (int ni = 0; ni < 4; ni++){
      const float bb = barr[ni];
      const int j = jh * 64 + 16 * ni + r15;
      float ps = 0.f;
#pragma unroll
      for (int mi = 0; mi < 4; mi++){
        float vals[4];
#pragma unroll
        for (int r = 0; r < 4; r++) vals[r] = acc1[mi][ni][r] + bb;
        if (jh == 0){
#pragma unroll
          for (int r = 0; r < 4; r++){ vals[r] = __expf(vals[r]); ps += vals[r]; }
        }
        uint2 pk;
        pk.x = cvtpk(vals[0], vals[1]);
        pk.y = cvtpk(vals[2], vals[3]);
        int g8 = 16 * th + 4 * mi + q;
        int g8s = g8 ^ (2 * r15);
        *(uint2*)&sekv[j * 128 + g8s * 4] = pk;
      }
      if (jh == 0){
        ps += __shfl_xor(ps, 16); ps += __shfl_xor(ps, 32);
        rs[ni] += ps;
      }
    }
    // B1 (lgkm-only): sekv writes visible; staging vmcnt NOT drained
    asm volatile("s_waitcnt lgkmcnt(0)" ::: "memory");
    __builtin_amdgcn_s_barrier();
    {
      bf16x8 ka[4], va[4];
      const int g8s = (8 * w + 2 * q) ^ (2 * r15);
#pragma unroll
      for (int mi2 = 0; mi2 < 4; mi2++){
        int d = 16 * mi2 + r15;
        ka[mi2] = *(const bf16x8*)&sekv[d * 128 + g8s * 4];
      }
#pragma unroll
      for (int ni2 = 0; ni2 < 4; ni2++){
        int e = 16 * ni2 + r15;
        va[ni2] = *(const bf16x8*)&sekv[(64 + e) * 128 + g8s * 4];
      }
#pragma unroll
      for (int mi2 = 0; mi2 < 4; mi2++)
#pragma unroll
        for (int ni2 = 0; ni2 < 4; ni2++)
          acc2[mi2][ni2] = __builtin_amdgcn_mfma_f32_16x16x32_bf16(
              ka[mi2], va[ni2], acc2[mi2][ni2], 0, 0, 0);
    }
    __syncthreads();   // B2 (full): staged sx ready; sekv consumed
  }
#undef STAGE
  float* fb = (float*)smem;
#pragma unroll
  for (int mi2 = 0; mi2 < 4; mi2++)
#pragma unroll
    for (int ni2 = 0; ni2 < 4; ni2++)
#pragma unroll
      for (int r = 0; r < 4; r++){
        int d = 16 * mi2 + 4 * q + r, e = 16 * ni2 + r15;
        fb[w * 4096 + d * 64 + e] = acc2[mi2][ni2][r];
      }
  __syncthreads();
  {
    float* dst = pctx + ((size_t)((b * 8 + h) * 32 + chunk)) * 4096 + tid * 16;
#pragma unroll
    for (int i = 0; i < 4; i++){
      int o = tid * 16 + 4 * i;
      float4 a = *(const float4*)(fb + o);
      float4 c = *(const float4*)(fb + 4096 + o);
      float4 d = *(const float4*)(fb + 8192 + o);
      float4 e = *(const float4*)(fb + 12288 + o);
      float4 s;
      s.x = a.x + c.x + d.x + e.x; s.y = a.y + c.y + d.y + e.y;
      s.z = a.z + c.z + d.z + e.z; s.w = a.w + c.w + d.w + e.w;
      *(float4*)(dst + 4 * i) = s;
    }
  }
  if (jh == 0 && q == 0){
    float* rb = prs + ((size_t)((b * 8 + h) * 32 + chunk)) * 128 + th * 64;
#pragma unroll
    for (int ni = 0; ni < 4; ni++) rb[16 * ni + r15] = rs[ni];
  }
}

// ---------------------------------------------------------------------------
// redmker v2 (R7-proven, unchanged): 256 blocks (32 bh x 8 d-slices).
// ---------------------------------------------------------------------------
__global__ __launch_bounds__(256) void redmker(const float* __restrict__ pctx,
    const float* __restrict__ prs, const float* __restrict__ Wo,
    u16* __restrict__ mtf){
  __shared__ float ctxh8[8][68];
  __shared__ float woht[64][132];
  __shared__ float rsh[8];
  const int tid = threadIdx.x;
  const int bh = blockIdx.x, s = blockIdx.y;
  const int h = bh & 7;
  { // stage Wo^T slice for head h
    const int e4 = tid & 15, r0 = tid >> 4;
#pragma unroll
    for (int p = 0; p < 8; p++){
      int c = r0 + p * 16;
      float4 v = *(const float4*)(Wo + (size_t)c * 512 + h * 64 + 4 * e4);
      woht[4 * e4 + 0][c] = v.x; woht[4 * e4 + 1][c] = v.y;
      woht[4 * e4 + 2][c] = v.z; woht[4 * e4 + 3][c] = v.w;
    }
  }
  { // reduce 32 chunk-partials of this 512-float slice (float2/thread)
    const float* base = pctx + (size_t)bh * 131072 + s * 512 + tid * 2;
    float2 a = {0.f, 0.f};
#pragma unroll 4
    for (int c = 0; c < 32; c++){
      float2 v = *(const float2*)(base + c * 4096);
      a.x += v.x; a.y += v.y;
    }
    const int i = tid * 2;
    ctxh8[i >> 6][i & 63] = a.x;
    ctxh8[(i + 1) >> 6][(i + 1) & 63] = a.y;
  }
  { // rowsum for the 8 d-rows of this slice
    const int dl = tid >> 5, c = tid & 31;
    const int dg = s * 8 + dl;
    const float* rb = prs + (size_t)bh * 4096 + c * 128;
    float v = rb[dg] + rb[64 + dg];
    v += __shfl_xor(v, 1);  v += __shfl_xor(v, 2);
    v += __shfl_xor(v, 4);  v += __shfl_xor(v, 8);
    v += __shfl_xor(v, 16);
    if (c == 0) rsh[dl] = v;
  }
  __syncthreads();
  const int dl = tid >> 5, c0 = (tid & 31) * 4;
  const int d = s * 8 + dl;
  const float inv = 1.f / rsh[dl];
  float acc[4] = {0.f, 0.f, 0.f, 0.f};
  for (int e = 0; e < 64; e++){
    float cv = ctxh8[dl][e];
#pragma unroll
    for (int j = 0; j < 4; j++) acc[j] += cv * woht[e][c0 + j];
  }
  const int ks = d >> 5, lq = ((d >> 3) & 3) << 4, el = d & 7;
#pragma unroll
  for (int j = 0; j < 4; j++){
    int c = c0 + j;
    mtf[((size_t)(bh * 8 + (c >> 4)) * 2 + ks) * 512 + ((c & 15) | lq) * 8 + el]
        = f2bf(inv * acc[j]);
  }
}

// ---------------------------------------------------------------------------
// qout v9: BOTH weight slabs (wqf(h) 16K + mtf(h) 16K) staged per head into
// LDS via global_load_lds (one fetch per block instead of per wave: weight
// L2 traffic 1 GiB -> 256 MiB) at UNCHANGED occupancy (40 KiB LDS, VGPR~60
// -> 3 blocks/CU, same as v4). Fragment layouts identical; only base ptr
// changes to LDS. 2 barriers/head. Accumulation order unchanged.
// ---------------------------------------------------------------------------
__global__ __launch_bounds__(256, 3) void qout(const u16* __restrict__ xt,
    const u16* __restrict__ wqf, const float* __restrict__ bqs,
    const u16* __restrict__ mtf, const float* __restrict__ bo,
    float* __restrict__ out){
  __shared__ u16 smWq[8192];      // wqf(h): 16 KiB
  __shared__ u16 smWm[8192];      // mtf(h): 16 KiB
  __shared__ u16 smP[4][16 * 64]; // per-wave p[16t][64d]: 8 KiB
  const int tid = threadIdx.x;
  const int tt = blockIdx.x, b = blockIdx.y;
  const int w = tid >> 6, l = tid & 63, r15 = l & 15, q = l >> 4;
  const int t0 = tt * 64;
  const int m7 = 2 * (r15 & 7);
  const int t = t0 + w * 16 + r15;

  // x B-frags for this wave's 16 tokens (h-independent, pre-swizzled xt)
  bf16x8 xb[4];
#pragma unroll
  for (int ks = 0; ks < 4; ks++)
    xb[ks] = *(const bf16x8*)(xt + (size_t)(b * N_ + t) * 128 +
                              (((ks * 4 + q) ^ r15) * 8));

  u16* sp = smP[w];
  f32x4 acc3[8] = {};
  for (int h = 0; h < 8; h++){
    // stage wqf(h) [waves 0,1] + mtf(h) [waves 2,3]: 32 KiB linear copy
    {
      const char* gsrc = (w < 2)
          ? (const char*)(wqf + (size_t)h * 8192) + w * 8192 + l * 16
          : (const char*)(mtf + (size_t)(b * 8 + h) * 8192) + (w - 2) * 8192 + l * 16;
      char* ldst = (w < 2) ? (char*)smWq + w * 8192
                           : (char*)smWm + (w - 2) * 8192;
#pragma unroll
      for (int p = 0; p < 8; p++)
        __builtin_amdgcn_global_load_lds(
            (const __attribute__((address_space(1))) void*)(gsrc + p * 1024),
            (__attribute__((address_space(3))) void*)(ldst + p * 1024), 16, 0, 0);
    }
    __syncthreads();   // vmcnt drained: weight slabs ready

    float bq_[4][4];
#pragma unroll
    for (int mi = 0; mi < 4; mi++){
      float4 v = *(const float4*)(bqs + h * 64 + 16 * mi + 4 * q);
      bq_[mi][0] = v.x; bq_[mi][1] = v.y; bq_[mi][2] = v.z; bq_[mi][3] = v.w;
    }
    // MFMA1: D[d 64][t 16], K=128; A = wq frags (LDS), B = xb (regs)
    f32x4 acc1[4] = {};
#pragma unroll
    for (int ks = 0; ks < 4; ks++){
      bf16x8 wqv[4];
#pragma unroll
      for (int mi = 0; mi < 4; mi++)
        wqv[mi] = *(const bf16x8*)&smWq[(mi * 4 + ks) * 512 + l * 8];
#pragma unroll
      for (int mi = 0; mi < 4; mi++)
        acc1[mi] = __builtin_amdgcn_mfma_f32_16x16x32_bf16(
            wqv[mi], xb[ks], acc1[mi], 0, 0, 0);
    }
    // exp + in-wave colsum + normalized p store (wave-private)
    {
      float ps = 0.f;
#pragma unroll
      for (int mi = 0; mi < 4; mi++)
#pragma unroll
        for (int r = 0; r < 4; r++){
          float e = __expf(acc1[mi][r] + bq_[mi][r]);
          acc1[mi][r] = e; ps += e;
        }
      ps += __shfl_xor(ps, 16); ps += __shfl_xor(ps, 32);
      const float ci = 1.f / ps;
#pragma unroll
      for (int mi = 0; mi < 4; mi++){
        uint2 pk;
        pk.x = cvtpk(acc1[mi][0] * ci, acc1[mi][1] * ci);
        pk.y = cvtpk(acc1[mi][2] * ci, acc1[mi][3] * ci);
        int g8s = (4 * mi + q) ^ m7;
        *(uint2*)&sp[r15 * 64 + g8s * 4] = pk;
      }
    }
    // MFMA2: out[c 128][t 16] += M_h . p, K=64; mf frags from LDS
#pragma unroll
    for (int ks2 = 0; ks2 < 2; ks2++){
      const int g8s = (8 * ks2 + 2 * q) ^ m7;
      bf16x8 pb = *(const bf16x8*)&sp[r15 * 64 + g8s * 4];
#pragma unroll
      for (int mm = 0; mm < 8; mm++){
        bf16x8 mf = *(const bf16x8*)&smWm[(mm * 2 + ks2) * 512 + l * 8];
        acc3[mm] = __builtin_amdgcn_mfma_f32_16x16x32_bf16(
            mf, pb, acc3[mm], 0, 0, 0);
      }
    }
    if (h < 7) __syncthreads();   // weights consumed -> safe to overwrite
  }
#pragma unroll
  for (int mi = 0; mi < 8; mi++){
    float4 bv = *(const float4*)(bo + 16 * mi + 4 * q);
    float bs[4] = {bv.x, bv.y, bv.z, bv.w};
#pragma unroll
    for (int r = 0; r < 4; r++){
      int c = 16 * mi + 4 * q + r;
      out[(size_t)(b * 128 + c) * N_ + t] = acc3[mi][r] + bs[r];
    }
  }
}

// ---------------------------------------------------------------------------
extern "C" void kernel_launch(void* const* d_in, const int* in_sizes, int n_in,
                              void* d_out, int out_size, void* d_ws, size_t ws_size,
                              hipStream_t stream){
  const float* x  = (const float*)d_in[0];
  const float* Wq = (const float*)d_in[1];
  const float* bq = (const float*)d_in[2];
  const float* Wk = (const float*)d_in[3];
  const float* bk = (const float*)d_in[4];
  const float* Wv = (const float*)d_in[5];
  const float* bv = (const float*)d_in[6];
  const float* Wo = (const float*)d_in[7];
  const float* bo = (const float*)d_in[8];
  float* out = (float*)d_out;

  char* ws = (char*)d_ws;
  u16*   xt     = (u16*)ws;                         // 16 MiB (pre-swizzled)
  u16*   wkvf   = (u16*)(ws + 16777216);            // 256 KiB
  u16*   wqf    = (u16*)(ws + 17039360);            // 128 KiB
  u16*   mtf    = (u16*)(ws + 17170432);            // 512 KiB
  float* bkv    = (float*)(ws + 17694720);          // 4 KiB
  float* bqs    = (float*)(ws + 17698816);          // 2 KiB
  float* pctx   = (float*)(ws + 18233344);          // 16 MiB
  float* prs    = (float*)(ws + 35010560);          // 512 KiB

  pconvx <<<608, 256, 0, stream>>>(x, xt, Wq, bq, Wk, bk, Wv, bv,
                                   wkvf, wqf, bkv, bqs);
  kvctx  <<<dim3(32, 8, 4), 256, 0, stream>>>(xt, wkvf, bkv, pctx, prs);
  redmker<<<dim3(32, 8), 256, 0, stream>>>(pctx, prs, Wo, mtf);
  qout   <<<dim3(256, 4), 256, 0, stream>>>(xt, wqf, bqs, mtf, bo, out);
}

// Round 12
// 162.594 us; speedup vs baseline: 3.6326x; 1.0485x over previous
//
#include <hip/hip_runtime.h>

typedef unsigned short u16;
typedef __bf16 bf16x8 __attribute__((ext_vector_type(8)));
typedef float f32x4 __attribute__((ext_vector_type(4)));

#define N_ 16384
#define SCALE 0.35355339059327379f   // 64^-0.25

__device__ __forceinline__ u16 f2bf(float f){
  union { float f; unsigned int i; } v; v.f = f;
  unsigned int b = v.i;
  return (u16)((b + 0x7FFFu + ((b >> 16) & 1u)) >> 16);
}
// packed RNE f32x2 -> bf16x2 (bit-identical to f2bf pair, 1 instr)
__device__ __forceinline__ unsigned int cvtpk(float a, float b){
  unsigned int r;
  asm("v_cvt_pk_bf16_f32 %0, %1, %2" : "=v"(r) : "v"(a), "v"(b));
  return r;
}

// ---------------------------------------------------------------------------
// pconvx = prep + convx fused (R7-proven, unchanged).
// ---------------------------------------------------------------------------
__global__ __launch_bounds__(256) void pconvx(const float* __restrict__ x,
    u16* __restrict__ xt, const float* __restrict__ Wq,
    const float* __restrict__ bq, const float* __restrict__ Wk,
    const float* __restrict__ bk, const float* __restrict__ Wv,
    const float* __restrict__ bv, u16* __restrict__ wkvf, u16* __restrict__ wqf,
    float* __restrict__ bkv, float* __restrict__ bqs){
  const int tid = threadIdx.x;
  const int bid = blockIdx.x;
  if (bid < 512){
    const int b = bid >> 7;
    const int kq = tid >> 6;                           // wave = k-quarter
    const int t0 = (bid & 127) * 128 + 2 * (tid & 63); // 2 tokens / thread
    const float* xp = x + (size_t)(b * 128 + kq * 32) * N_ + t0;
    u16* dst = xt + (size_t)(b * N_ + t0) * 128;
#pragma unroll
    for (int gi = 0; gi < 4; gi++){
      float2 v[8];
#pragma unroll
      for (int j = 0; j < 8; j++)
        v[j] = *(const float2*)(xp + (size_t)(gi * 8 + j) * N_);
      const int g = kq * 4 + gi;
      {
        uint4 o;
        o.x = cvtpk(v[0].x, v[1].x); o.y = cvtpk(v[2].x, v[3].x);
        o.z = cvtpk(v[4].x, v[5].x); o.w = cvtpk(v[6].x, v[7].x);
        *(uint4*)(dst + ((g ^ (t0 & 15)) * 8)) = o;
      }
      {
        uint4 o;
        o.x = cvtpk(v[0].y, v[1].y); o.y = cvtpk(v[2].y, v[3].y);
        o.z = cvtpk(v[4].y, v[5].y); o.w = cvtpk(v[6].y, v[7].y);
        const int t = t0 + 1;
        *(uint4*)(dst + 128 + ((g ^ (t & 15)) * 8)) = o;
      }
    }
    return;
  }
  // ---- prep path ----
  const int T = (bid - 512) * 256 + tid;   // 0..24575
  if (T < 1024){
    int jj = T & 127, h = T >> 7;
    bkv[T] = (jj < 64) ? SCALE * bk[h * 64 + jj] : bv[h * 64 + jj - 64];
  } else if (T < 1536){
    bqs[T - 1024] = SCALE * bq[T - 1024];
  }
  const float* src; float sc; u16* dst;
  if (T < 16384){
    int l = T & 63, f = T >> 6;
    int ks = f & 3, jt = (f >> 2) & 7, h = f >> 5;
    int jj = 16 * jt + (l & 15);
    int k0 = ks * 32 + (l >> 4) * 8;
    if (jj < 64){ src = Wk + (size_t)(h * 64 + jj) * 128 + k0; sc = SCALE; }
    else        { src = Wv + (size_t)(h * 64 + jj - 64) * 128 + k0; sc = 1.f; }
    dst = wkvf + (size_t)f * 512 + l * 8;
  } else {
    int T2 = T - 16384;
    int l = T2 & 63, f = T2 >> 6;
    int ks = f & 3, dt = (f >> 2) & 3, h = f >> 4;
    int d = 16 * dt + (l & 15);
    int k0 = ks * 32 + (l >> 4) * 8;
    src = Wq + (size_t)(h * 64 + d) * 128 + k0; sc = SCALE;
    dst = wqf + (size_t)f * 512 + l * 8;
  }
  float4 a = *(const float4*)src, c = *(const float4*)(src + 4);
  ushort4 o0, o1;
  o0.x = f2bf(sc * a.x); o0.y = f2bf(sc * a.y); o0.z = f2bf(sc * a.z); o0.w = f2bf(sc * a.w);
  o1.x = f2bf(sc * c.x); o1.y = f2bf(sc * c.y); o1.z = f2bf(sc * c.z); o1.w = f2bf(sc * c.w);
  *(ushort4*)dst = o0; *(ushort4*)(dst + 4) = o1;
}

// ---------------------------------------------------------------------------
// kvctx v10: R4 structure + (a) balanced exp: every wave owns 2 K-tiles +
// 2 V-tiles (jt = ni<2 ? 2jh+ni : 2+2jh+ni) so exp work is uniform across
// waves; (b) chunk-pairing: 512 blocks (one residency round), each processes
// 2 chunks (8 subs), acc2/rs accumulate across both -> pctx halves to 8 MB.
// Same sekv bijection, same barrier cadence, same staging.
// ---------------------------------------------------------------------------
__global__ __launch_bounds__(256, 2) void kvctx(const u16* __restrict__ xt,
    const u16* __restrict__ wkvf, const float* __restrict__ bkv,
    float* __restrict__ pctx, float* __restrict__ prs){
  __shared__ u16 smem[32768];   // sx [0,32768)B ; sekv [32768,65536)B ; fb overlay
  const int tid = threadIdx.x;
  const int cp = blockIdx.x, h = blockIdx.y, b = blockIdx.z;  // cp = chunk pair
  const int w = tid >> 6, l = tid & 63, r15 = l & 15, q = l >> 4;
  const int th = w & 1, jh = w >> 1;

  // balanced j-tile map: ni 0,1 -> K-tiles 2jh+ni (rows<64, exp'd);
  //                      ni 2,3 -> V-tiles 4+2jh+(ni-2) (rows>=64)
  int jt_[4];
#pragma unroll
  for (int ni = 0; ni < 4; ni++) jt_[ni] = (ni < 2) ? (2 * jh + ni) : (2 + 2 * jh + ni);

  bf16x8 wf[4][4];
#pragma unroll
  for (int ni = 0; ni < 4; ni++)
#pragma unroll
    for (int ks = 0; ks < 4; ks++)
      wf[ni][ks] = *(const bf16x8*)(wkvf +
          (size_t)((h * 8 + jt_[ni]) * 4 + ks) * 512 + l * 8);
  float barr[4];
#pragma unroll
  for (int ni = 0; ni < 4; ni++)
    barr[ni] = bkv[h * 128 + jt_[ni] * 16 + r15];

  const size_t tok0 = (size_t)b * N_ + cp * 1024;
  const char* gbase = (const char*)(xt + tok0 * 128);  // 1024 rows x 256 B
  u16* sekv = smem + 16384;

#define STAGE(sub_)                                                            \
  {                                                                            \
    const char* gs = gbase + (size_t)(sub_)*32768 + w * 8192 + l * 16;         \
    char* ls = (char*)smem + w * 8192;                                         \
    _Pragma("unroll")                                                          \
    for (int p = 0; p < 8; p++)                                                \
      __builtin_amdgcn_global_load_lds(                                        \
          (const __attribute__((address_space(1))) void*)(gs + p * 1024),      \
          (__attribute__((address_space(3))) void*)(ls + p * 1024), 16, 0, 0); \
  }

  STAGE(0);
  __syncthreads();   // sub0 x-tile ready

  f32x4 acc2[4][4] = {};
  float rs[2] = {0.f, 0.f};

  for (int sub = 0; sub < 8; sub++){
    f32x4 acc1[4][4] = {};
#pragma unroll
    for (int ks = 0; ks < 4; ks++){
      bf16x8 xa[4];
#pragma unroll
      for (int mi = 0; mi < 4; mi++){
        int t = th * 64 + 16 * mi + r15;
        xa[mi] = *(const bf16x8*)&smem[t * 128 + (((ks * 4 + q) ^ r15) * 8)];
      }
#pragma unroll
      for (int mi = 0; mi < 4; mi++)
#pragma unroll
        for (int ni = 0; ni < 4; ni++)
          acc1[mi][ni] = __builtin_amdgcn_mfma_f32_16x16x32_bf16(
              xa[mi], wf[ni][ks], acc1[mi][ni], 0, 0, 0);
    }
    // B0 (lgkm-only): all waves done READING sx -> safe to overwrite
    asm volatile("s_waitcnt lgkmcnt(0)" ::: "memory");
    __builtin_amdgcn_s_barrier();
    if (sub < 7) STAGE(sub + 1);   // flies under softmax + MFMA2
#pragma unroll
    for (int ni = 0; ni < 4; ni++){
      const float bb = barr[ni];
      const int j = jt_[ni] * 16 + r15;
      float ps = 0.f;
#pragma unroll
      for (int mi = 0; mi < 4; mi++){
        float vals[4];
#pragma unroll
        for (int r = 0; r < 4; r++) vals[r] = acc1[mi][ni][r] + bb;
        if (ni < 2){
#pragma unroll
          for (int r = 0; r < 4; r++){ vals[r] = __expf(vals[r]); ps += vals[r]; }
        }
        uint2 pk;
        pk.x = cvtpk(vals[0], vals[1]);
        pk.y = cvtpk(vals[2], vals[3]);
        int g8 = 16 * th + 4 * mi + q;
        int g8s = g8 ^ (2 * r15);
        *(uint2*)&sekv[j * 128 + g8s * 4] = pk;
      }
      if (ni < 2){
        ps += __shfl_xor(ps, 16); ps += __shfl_xor(ps, 32);
        rs[ni] += ps;
      }
    }
    // B1 (lgkm-only): sekv writes visible; staging vmcnt NOT drained
    asm volatile("s_waitcnt lgkmcnt(0)" ::: "memory");
    __builtin_amdgcn_s_barrier();
    {
      bf16x8 ka[4], va[4];
      const int g8s = (8 * w + 2 * q) ^ (2 * r15);
#pragma unroll
      for (int mi2 = 0; mi2 < 4; mi2++){
        int d = 16 * mi2 + r15;
        ka[mi2] = *(const bf16x8*)&sekv[d * 128 + g8s * 4];
      }
#pragma unroll
      for (int ni2 = 0; ni2 < 4; ni2++){
        int e = 16 * ni2 + r15;
        va[ni2] = *(const bf16x8*)&sekv[(64 + e) * 128 + g8s * 4];
      }
#pragma unroll
      for (int mi2 = 0; mi2 < 4; mi2++)
#pragma unroll
        for (int ni2 = 0; ni2 < 4; ni2++)
          acc2[mi2][ni2] = __builtin_amdgcn_mfma_f32_16x16x32_bf16(
              ka[mi2], va[ni2], acc2[mi2][ni2], 0, 0, 0);
    }
    __syncthreads();   // B2 (full): staged sx ready; sekv consumed
  }
#undef STAGE
  float* fb = (float*)smem;
#pragma unroll
  for (int mi2 = 0; mi2 < 4; mi2++)
#pragma unroll
    for (int ni2 = 0; ni2 < 4; ni2++)
#pragma unroll
      for (int r = 0; r < 4; r++){
        int d = 16 * mi2 + 4 * q + r, e = 16 * ni2 + r15;
        fb[w * 4096 + d * 64 + e] = acc2[mi2][ni2][r];
      }
  __syncthreads();
  {
    float* dst = pctx + ((size_t)((b * 8 + h) * 16 + cp)) * 4096 + tid * 16;
#pragma unroll
    for (int i = 0; i < 4; i++){
      int o = tid * 16 + 4 * i;
      float4 a = *(const float4*)(fb + o);
      float4 c = *(const float4*)(fb + 4096 + o);
      float4 d = *(const float4*)(fb + 8192 + o);
      float4 e = *(const float4*)(fb + 12288 + o);
      float4 s;
      s.x = a.x + c.x + d.x + e.x; s.y = a.y + c.y + d.y + e.y;
      s.z = a.z + c.z + d.z + e.z; s.w = a.w + c.w + d.w + e.w;
      *(float4*)(dst + 4 * i) = s;
    }
  }
  if (q == 0){
    float* rb = prs + ((size_t)((b * 8 + h) * 16 + cp)) * 128 + th * 64 + 32 * jh;
#pragma unroll
    for (int ni = 0; ni < 2; ni++) rb[16 * ni + r15] = rs[ni];
  }
}

// ---------------------------------------------------------------------------
// redmker v3: 16 chunk-pair partials (was 32 chunks). 256 blocks.
// ---------------------------------------------------------------------------
__global__ __launch_bounds__(256) void redmker(const float* __restrict__ pctx,
    const float* __restrict__ prs, const float* __restrict__ Wo,
    u16* __restrict__ mtf){
  __shared__ float ctxh8[8][68];
  __shared__ float woht[64][132];
  __shared__ float rsh[8];
  const int tid = threadIdx.x;
  const int bh = blockIdx.x, s = blockIdx.y;
  const int h = bh & 7;
  { // stage Wo^T slice for head h
    const int e4 = tid & 15, r0 = tid >> 4;
#pragma unroll
    for (int p = 0; p < 8; p++){
      int c = r0 + p * 16;
      float4 v = *(const float4*)(Wo + (size_t)c * 512 + h * 64 + 4 * e4);
      woht[4 * e4 + 0][c] = v.x; woht[4 * e4 + 1][c] = v.y;
      woht[4 * e4 + 2][c] = v.z; woht[4 * e4 + 3][c] = v.w;
    }
  }
  { // reduce 16 cp-partials of this 512-float slice (float2/thread)
    const float* base = pctx + (size_t)bh * 65536 + s * 512 + tid * 2;
    float2 a = {0.f, 0.f};
#pragma unroll 4
    for (int c = 0; c < 16; c++){
      float2 v = *(const float2*)(base + c * 4096);
      a.x += v.x; a.y += v.y;
    }
    const int i = tid * 2;
    ctxh8[i >> 6][i & 63] = a.x;
    ctxh8[(i + 1) >> 6][(i + 1) & 63] = a.y;
  }
  { // rowsum for the 8 d-rows of this slice (16 cps on lanes 0..15)
    const int dl = tid >> 5, c = tid & 31;
    const int dg = s * 8 + dl;
    float v = 0.f;
    if (c < 16){
      const float* rb = prs + (size_t)bh * 2048 + c * 128;
      v = rb[dg] + rb[64 + dg];
    }
    v += __shfl_xor(v, 1);  v += __shfl_xor(v, 2);
    v += __shfl_xor(v, 4);  v += __shfl_xor(v, 8);
    v += __shfl_xor(v, 16);
    if (c == 0) rsh[dl] = v;
  }
  __syncthreads();
  const int dl = tid >> 5, c0 = (tid & 31) * 4;
  const int d = s * 8 + dl;
  const float inv = 1.f / rsh[dl];
  float acc[4] = {0.f, 0.f, 0.f, 0.f};
  for (int e = 0; e < 64; e++){
    float cv = ctxh8[dl][e];
#pragma unroll
    for (int j = 0; j < 4; j++) acc[j] += cv * woht[e][c0 + j];
  }
  const int ks = d >> 5, lq = ((d >> 3) & 3) << 4, el = d & 7;
#pragma unroll
  for (int j = 0; j < 4; j++){
    int c = c0 + j;
    mtf[((size_t)(bh * 8 + (c >> 4)) * 2 + ks) * 512 + ((c & 15) | lq) * 8 + el]
        = f2bf(inv * acc[j]);
  }
}

// ---------------------------------------------------------------------------
// qout v9 (R11-measured, unchanged): both weight slabs staged per head into
// LDS at unchanged occupancy.
// ---------------------------------------------------------------------------
__global__ __launch_bounds__(256, 3) void qout(const u16* __restrict__ xt,
    const u16* __restrict__ wqf, const float* __restrict__ bqs,
    const u16* __restrict__ mtf, const float* __restrict__ bo,
    float* __restrict__ out){
  __shared__ u16 smWq[8192];      // wqf(h): 16 KiB
  __shared__ u16 smWm[8192];      // mtf(h): 16 KiB
  __shared__ u16 smP[4][16 * 64]; // per-wave p[16t][64d]: 8 KiB
  const int tid = threadIdx.x;
  const int tt = blockIdx.x, b = blockIdx.y;
  const int w = tid >> 6, l = tid & 63, r15 = l & 15, q = l >> 4;
  const int t0 = tt * 64;
  const int m7 = 2 * (r15 & 7);
  const int t = t0 + w * 16 + r15;

  // x B-frags for this wave's 16 tokens (h-independent, pre-swizzled xt)
  bf16x8 xb[4];
#pragma unroll
  for (int ks = 0; ks < 4; ks++)
    xb[ks] = *(const bf16x8*)(xt + (size_t)(b * N_ + t) * 128 +
                              (((ks * 4 + q) ^ r15) * 8));

  u16* sp = smP[w];
  f32x4 acc3[8] = {};
  for (int h = 0; h < 8; h++){
    // stage wqf(h) [waves 0,1] + mtf(h) [waves 2,3]: 32 KiB linear copy
    {
      const char* gsrc = (w < 2)
          ? (const char*)(wqf + (size_t)h * 8192) + w * 8192 + l * 16
          : (const char*)(mtf + (size_t)(b * 8 + h) * 8192) + (w - 2) * 8192 + l * 16;
      char* ldst = (w < 2) ? (char*)smWq + w * 8192
                           : (char*)smWm + (w - 2) * 8192;
#pragma unroll
      for (int p = 0; p < 8; p++)
        __builtin_amdgcn_global_load_lds(
            (const __attribute__((address_space(1))) void*)(gsrc + p * 1024),
            (__attribute__((address_space(3))) void*)(ldst + p * 1024), 16, 0, 0);
    }
    __syncthreads();   // vmcnt drained: weight slabs ready

    float bq_[4][4];
#pragma unroll
    for (int mi = 0; mi < 4; mi++){
      float4 v = *(const float4*)(bqs + h * 64 + 16 * mi + 4 * q);
      bq_[mi][0] = v.x; bq_[mi][1] = v.y; bq_[mi][2] = v.z; bq_[mi][3] = v.w;
    }
    // MFMA1: D[d 64][t 16], K=128; A = wq frags (LDS), B = xb (regs)
    f32x4 acc1[4] = {};
#pragma unroll
    for (int ks = 0; ks < 4; ks++){
      bf16x8 wqv[4];
#pragma unroll
      for (int mi = 0; mi < 4; mi++)
        wqv[mi] = *(const bf16x8*)&smWq[(mi * 4 + ks) * 512 + l * 8];
#pragma unroll
      for (int mi = 0; mi < 4; mi++)
        acc1[mi] = __builtin_amdgcn_mfma_f32_16x16x32_bf16(
            wqv[mi], xb[ks], acc1[mi], 0, 0, 0);
    }
    // exp + in-wave colsum + normalized p store (wave-private)
    {
      float ps = 0.f;
#pragma unroll
      for (int mi = 0; mi < 4; mi++)
#pragma unroll
        for (int r = 0; r < 4; r++){
          float e = __expf(acc1[mi][r] + bq_[mi][r]);
          acc1[mi][r] = e; ps += e;
        }
      ps += __shfl_xor(ps, 16); ps += __shfl_xor(ps, 32);
      const float ci = 1.f / ps;
#pragma unroll
      for (int mi = 0; mi < 4; mi++){
        uint2 pk;
        pk.x = cvtpk(acc1[mi][0] * ci, acc1[mi][1] * ci);
        pk.y = cvtpk(acc1[mi][2] * ci, acc1[mi][3] * ci);
        int g8s = (4 * mi + q) ^ m7;
        *(uint2*)&sp[r15 * 64 + g8s * 4] = pk;
      }
    }
    // MFMA2: out[c 128][t 16] += M_h . p, K=64; mf frags from LDS
#pragma unroll
    for (int ks2 = 0; ks2 < 2; ks2++){
      const int g8s = (8 * ks2 + 2 * q) ^ m7;
      bf16x8 pb = *(const bf16x8*)&sp[r15 * 64 + g8s * 4];
#pragma unroll
      for (int mm = 0; mm < 8; mm++){
        bf16x8 mf = *(const bf16x8*)&smWm[(mm * 2 + ks2) * 512 + l * 8];
        acc3[mm] = __builtin_amdgcn_mfma_f32_16x16x32_bf16(
            mf, pb, acc3[mm], 0, 0, 0);
      }
    }
    if (h < 7) __syncthreads();   // weights consumed -> safe to overwrite
  }
#pragma unroll
  for (int mi = 0; mi < 8; mi++){
    float4 bv = *(const float4*)(bo + 16 * mi + 4 * q);
    float bs[4] = {bv.x, bv.y, bv.z, bv.w};
#pragma unroll
    for (int r = 0; r < 4; r++){
      int c = 16 * mi + 4 * q + r;
      out[(size_t)(b * 128 + c) * N_ + t] = acc3[mi][r] + bs[r];
    }
  }
}

// ---------------------------------------------------------------------------
extern "C" void kernel_launch(void* const* d_in, const int* in_sizes, int n_in,
                              void* d_out, int out_size, void* d_ws, size_t ws_size,
                              hipStream_t stream){
  const float* x  = (const float*)d_in[0];
  const float* Wq = (const float*)d_in[1];
  const float* bq = (const float*)d_in[2];
  const float* Wk = (const float*)d_in[3];
  const float* bk = (const float*)d_in[4];
  const float* Wv = (const float*)d_in[5];
  const float* bv = (const float*)d_in[6];
  const float* Wo = (const float*)d_in[7];
  const float* bo = (const float*)d_in[8];
  float* out = (float*)d_out;

  char* ws = (char*)d_ws;
  u16*   xt     = (u16*)ws;                         // 16 MiB (pre-swizzled)
  u16*   wkvf   = (u16*)(ws + 16777216);            // 256 KiB
  u16*   wqf    = (u16*)(ws + 17039360);            // 128 KiB
  u16*   mtf    = (u16*)(ws + 17170432);            // 512 KiB
  float* bkv    = (float*)(ws + 17694720);          // 4 KiB
  float* bqs    = (float*)(ws + 17698816);          // 2 KiB
  float* pctx   = (float*)(ws + 18233344);          // 8 MiB (16 cp-partials)
  float* prs    = (float*)(ws + 35010560);          // 256 KiB

  pconvx <<<608, 256, 0, stream>>>(x, xt, Wq, bq, Wk, bk, Wv, bv,
                                   wkvf, wqf, bkv, bqs);
  kvctx  <<<dim3(16, 8, 4), 256, 0, stream>>>(xt, wkvf, bkv, pctx, prs);
  redmker<<<dim3(32, 8), 256, 0, stream>>>(pctx, prs, Wo, mtf);
  qout   <<<dim3(256, 4), 256, 0, stream>>>(xt, wqf, bqs, mtf, bo, out);
}